// Round 1
// baseline (3767.641 us; speedup 1.0000x reference)
//
#include <hip/hip_runtime.h>
#include <math.h>

#define LEAK 0.01f
#define BNEPS 1e-5f

// ---------------- degree ----------------
__global__ void k_deg(const int* __restrict__ dst, float* __restrict__ deg, int E) {
  int e = blockIdx.x * blockDim.x + threadIdx.x;
  if (e < E) atomicAdd(&deg[dst[e]], 1.0f);
}

__global__ void k_dinv(const float* __restrict__ deg, float* __restrict__ dinv,
                       float* __restrict__ invcnt, int n) {
  int v = blockIdx.x * blockDim.x + threadIdx.x;
  if (v < n) {
    float d = deg[v];
    dinv[v]   = rsqrtf(d + 1.0f);      // GCN: deg includes self-loop
    invcnt[v] = 1.0f / fmaxf(d, 1.0f); // SAGE mean divisor
  }
}

// ---------------- GEMM: Y[n,FOUT] = X1[n,K](*rs1)@Wa (+ X2@Wb) (+bias) -----
template<int K, int FOUT, int ROWS, bool DUAL>
__global__ __launch_bounds__(ROWS*(FOUT/4)) void k_gemm(
    const float* __restrict__ X1, const float* __restrict__ rs1,
    const float* __restrict__ Wa,
    const float* __restrict__ X2, const float* __restrict__ Wb,
    const float* __restrict__ bias,
    float* __restrict__ Y, int n) {
  constexpr int TPR = FOUT / 4;
  constexpr int NT  = ROWS * TPR;          // block size (256 for all instances)
  constexpr int WCAP = 8192;               // max floats of LDS for W tiles (32 KB)
  constexpr int KC = ((K * FOUT * (DUAL ? 2 : 1)) <= WCAP)
                        ? K : (WCAP / (FOUT * (DUAL ? 2 : 1)));
  __shared__ float sX1[ROWS * K];
  __shared__ float sX2[DUAL ? ROWS * K : 1];
  __shared__ float sWa[KC * FOUT];
  __shared__ float sWb[DUAL ? KC * FOUT : 1];

  const int row0 = blockIdx.x * ROWS;
  for (int i = threadIdx.x; i < ROWS * K; i += NT) {
    int r = i / K, k = i % K;
    int gr = row0 + r;
    float v = 0.f, v2 = 0.f;
    if (gr < n) {
      v = X1[(long long)gr * K + k];
      if (rs1) v *= rs1[gr];
      if constexpr (DUAL) v2 = X2[(long long)gr * K + k];
    }
    sX1[i] = v;
    if constexpr (DUAL) sX2[i] = v2;
  }

  const int r  = threadIdx.x / TPR;
  const int jc = (threadIdx.x % TPR) * 4;
  float ax = 0.f, ay = 0.f, az = 0.f, aw = 0.f;
  for (int k0 = 0; k0 < K; k0 += KC) {
    __syncthreads();
    for (int i = threadIdx.x; i < KC * FOUT; i += NT) {
      int kk = i / FOUT, j = i % FOUT;
      sWa[i] = Wa[(long long)(k0 + kk) * FOUT + j];
      if constexpr (DUAL) sWb[i] = Wb[(long long)(k0 + kk) * FOUT + j];
    }
    __syncthreads();
#pragma unroll 8
    for (int kk = 0; kk < KC; kk++) {
      float xv = sX1[r * K + k0 + kk];
      const float4 w = *(const float4*)&sWa[kk * FOUT + jc];
      ax = fmaf(xv, w.x, ax); ay = fmaf(xv, w.y, ay);
      az = fmaf(xv, w.z, az); aw = fmaf(xv, w.w, aw);
      if constexpr (DUAL) {
        float x2 = sX2[r * K + k0 + kk];
        const float4 wb = *(const float4*)&sWb[kk * FOUT + jc];
        ax = fmaf(x2, wb.x, ax); ay = fmaf(x2, wb.y, ay);
        az = fmaf(x2, wb.z, az); aw = fmaf(x2, wb.w, aw);
      }
    }
  }
  int gr = row0 + r;
  if (gr < n) {
    if (bias) {
      ax += bias[jc + 0]; ay += bias[jc + 1];
      az += bias[jc + 2]; aw += bias[jc + 3];
    }
    float4 o; o.x = ax; o.y = ay; o.z = az; o.w = aw;
    *(float4*)&Y[(long long)gr * FOUT + jc] = o;
  }
}

// ---------------- GCN epilogue pieces ----------------
// A[v] = bias + H[v] * dinv[v]^2  (self-loop term; initializes accumulator)
template<int F>
__global__ void k_selfloop(const float* __restrict__ H, const float* __restrict__ dinv,
                           const float* __restrict__ bias, float* __restrict__ A, int n) {
  constexpr int TPR = F / 4;
  long long idx = (long long)blockIdx.x * blockDim.x + threadIdx.x;
  if (idx >= (long long)n * TPR) return;
  int v  = (int)(idx / TPR);
  int fc = (int)(idx % TPR) * 4;
  float w = dinv[v]; w *= w;
  const float4 h = *(const float4*)&H[(long long)v * F + fc];
  float4 o;
  o.x = fmaf(h.x, w, bias[fc + 0]);
  o.y = fmaf(h.y, w, bias[fc + 1]);
  o.z = fmaf(h.z, w, bias[fc + 2]);
  o.w = fmaf(h.w, w, bias[fc + 3]);
  *(float4*)&A[(long long)v * F + fc] = o;
}

// A[dst] += H[src] * (NORM ? dinv[s]*dinv[d] : 1)
template<int F, bool NORM>
__global__ void k_scatter(const float* __restrict__ H, const float* __restrict__ dinv,
                          const int* __restrict__ src, const int* __restrict__ dst,
                          float* __restrict__ A, int E) {
  constexpr int TPE = F / 4;
  long long idx = (long long)blockIdx.x * blockDim.x + threadIdx.x;
  if (idx >= (long long)E * TPE) return;
  int e  = (int)(idx / TPE);
  int fc = (int)(idx % TPE) * 4;
  int s = src[e], d = dst[e];
  float w = 1.0f;
  if constexpr (NORM) w = dinv[s] * dinv[d];
  const float4 h = *(const float4*)&H[(long long)s * F + fc];
  float* out = &A[(long long)d * F + fc];
  atomicAdd(out + 0, h.x * w);
  atomicAdd(out + 1, h.y * w);
  atomicAdd(out + 2, h.z * w);
  atomicAdd(out + 3, h.w * w);
}

// ---------------- BatchNorm (training forward, biased var) + LeakyReLU ------
template<int F>
__global__ void k_bn_stats(const float* __restrict__ Y, float* __restrict__ stats, int n) {
  constexpr int RPB = 256 / F;
  int f  = threadIdx.x % F;
  int r0 = threadIdx.x / F;
  float s1 = 0.f, s2 = 0.f;
  for (long long r = (long long)blockIdx.x * RPB + r0; r < n; r += (long long)gridDim.x * RPB) {
    float v = Y[r * F + f];
    s1 += v; s2 += v * v;
  }
  __shared__ float ls1[256], ls2[256];
  ls1[threadIdx.x] = s1; ls2[threadIdx.x] = s2;
  __syncthreads();
  if (r0 == 0) {
#pragma unroll
    for (int i = 1; i < RPB; i++) { s1 += ls1[i * F + f]; s2 += ls2[i * F + f]; }
    atomicAdd(&stats[f], s1);
    atomicAdd(&stats[F + f], s2);
  }
}

__global__ void k_bn_finalize(float* __restrict__ stats, const float* __restrict__ g,
                              const float* __restrict__ be, int F, float invN) {
  int f = blockIdx.x * blockDim.x + threadIdx.x;
  if (f >= F) return;
  float m   = stats[f] * invN;
  float var = stats[F + f] * invN - m * m;
  float sc  = g[f] * rsqrtf(var + BNEPS);
  stats[2 * F + f] = sc;
  stats[3 * F + f] = be[f] - m * sc;
}

template<int F>
__global__ void k_bn_apply(float* __restrict__ Y, const float* __restrict__ stats, int n) {
  constexpr int TPR = F / 4;
  long long idx = (long long)blockIdx.x * blockDim.x + threadIdx.x;
  if (idx >= (long long)n * TPR) return;
  int fc = (int)(idx % TPR) * 4;
  const float4 sc = *(const float4*)&stats[2 * F + fc];
  const float4 sh = *(const float4*)&stats[3 * F + fc];
  float4 y = *(float4*)&Y[idx * 4];
  y.x = fmaf(y.x, sc.x, sh.x); y.x = (y.x >= 0.f) ? y.x : LEAK * y.x;
  y.y = fmaf(y.y, sc.y, sh.y); y.y = (y.y >= 0.f) ? y.y : LEAK * y.y;
  y.z = fmaf(y.z, sc.z, sh.z); y.z = (y.z >= 0.f) ? y.z : LEAK * y.z;
  y.w = fmaf(y.w, sc.w, sh.w); y.w = (y.w >= 0.f) ? y.w : LEAK * y.w;
  *(float4*)&Y[idx * 4] = y;
}

// ---------------- pooling + link prediction ----------------
__global__ void k_pool(const float* __restrict__ A, const int* __restrict__ batch,
                       float* __restrict__ g, int n) {
  long long idx = (long long)blockIdx.x * blockDim.x + threadIdx.x;
  if (idx >= (long long)n * 8) return;
  int v  = (int)(idx / 8);
  int fc = (int)(idx % 8) * 4;
  int b  = batch[v];
  const float4 a = *(const float4*)&A[(long long)v * 32 + fc];
  float* out = &g[(long long)b * 32 + fc];
  atomicAdd(out + 0, a.x);
  atomicAdd(out + 1, a.y);
  atomicAdd(out + 2, a.z);
  atomicAdd(out + 3, a.w);
}

__global__ void k_link(const float* __restrict__ g, const int* __restrict__ li0,
                       const int* __restrict__ li1, float* __restrict__ out, int L) {
  int i = blockIdx.x * blockDim.x + threadIdx.x;
  if (i >= L) return;
  const float* a = g + (long long)li0[i] * 32;
  const float* b = g + (long long)li1[i] * 32;
  float s = 0.f;
#pragma unroll
  for (int f = 0; f < 32; f++) s = fmaf(a[f], b[f], s);
  out[i] = 1.0f / (1.0f + expf(-s));
}

// ---------------- launch ----------------
extern "C" void kernel_launch(void* const* d_in, const int* in_sizes, int n_in,
                              void* d_out, int out_size, void* d_ws, size_t ws_size,
                              hipStream_t stream) {
  const float* x   = (const float*)d_in[0];
  const int* ei    = (const int*)d_in[1];
  const int* batch = (const int*)d_in[2];
  const int* li    = (const int*)d_in[3];
  // d_in[4] = num_graphs (device scalar; G=1000 — pool buffer padded to 4096)
  const float* W1  = (const float*)d_in[5];
  const float* b1  = (const float*)d_in[6];
  const float* g1  = (const float*)d_in[7];
  const float* be1 = (const float*)d_in[8];
  const float* Wl2 = (const float*)d_in[9];
  const float* bl2 = (const float*)d_in[10];
  const float* Wr2 = (const float*)d_in[11];
  const float* g2  = (const float*)d_in[12];
  const float* be2 = (const float*)d_in[13];
  const float* W3  = (const float*)d_in[14];
  const float* b3  = (const float*)d_in[15];
  const float* g3  = (const float*)d_in[16];
  const float* be3 = (const float*)d_in[17];
  const float* W4  = (const float*)d_in[18];
  const float* b4  = (const float*)d_in[19];

  const int n = in_sizes[0] / 128;   // 50000
  const int E = in_sizes[1] / 2;     // 800000
  const int L = in_sizes[3] / 2;     // 1000
  const int* src = ei;
  const int* dst = ei + E;
  const int* li0 = li;
  const int* li1 = li + L;

  char* base = (char*)d_ws;
  size_t off = 0;
  auto alloc = [&](size_t bytes) -> float* {
    float* p = (float*)(base + off);
    off = (off + bytes + 255) & ~(size_t)255;
    return p;
  };
  float* deg    = alloc((size_t)n * 4);
  float* dinv   = alloc((size_t)n * 4);
  float* invcnt = alloc((size_t)n * 4);
  float* stats  = alloc(512 * 4);
  float* gpool  = alloc((size_t)4096 * 32 * 4);
  float* bufA   = alloc((size_t)n * 128 * 4);  // h1 / h3 / h4
  float* bufB   = alloc((size_t)n * 128 * 4);  // a1 / a3
  float* bufC   = alloc((size_t)n * 128 * 4);  // agg2 / a4
  float* bufD   = alloc((size_t)n * 64 * 4);   // h2
  (void)ws_size; (void)n_in; (void)out_size;

  const int BT = 256;
  auto cdiv = [](long long a, long long b) { return (int)((a + b - 1) / b); };

  // degrees & norms
  hipMemsetAsync(deg, 0, (size_t)n * 4, stream);
  k_deg<<<cdiv(E, BT), BT, 0, stream>>>(dst, deg, E);
  k_dinv<<<cdiv(n, BT), BT, 0, stream>>>(deg, dinv, invcnt, n);

  // ---- L1: GCN 128->128, BN, LReLU ----
  k_gemm<128,128,8,false><<<cdiv(n,8), 256, 0, stream>>>(x, nullptr, W1, nullptr, nullptr, nullptr, bufA, n);
  k_selfloop<128><<<cdiv((long long)n*32, BT), BT, 0, stream>>>(bufA, dinv, b1, bufB, n);
  k_scatter<128,true><<<cdiv((long long)E*32, BT), BT, 0, stream>>>(bufA, dinv, src, dst, bufB, E);
  hipMemsetAsync(stats, 0, 2 * 128 * 4, stream);
  k_bn_stats<128><<<256, 256, 0, stream>>>(bufB, stats, n);
  k_bn_finalize<<<1, 128, 0, stream>>>(stats, g1, be1, 128, 1.0f / n);
  k_bn_apply<128><<<cdiv((long long)n*32, BT), BT, 0, stream>>>(bufB, stats, n);

  // ---- L2: SAGE 128->64, BN, LReLU ----
  hipMemsetAsync(bufC, 0, (size_t)n * 128 * 4, stream);
  k_scatter<128,false><<<cdiv((long long)E*32, BT), BT, 0, stream>>>(bufB, dinv, src, dst, bufC, E);
  k_gemm<128,64,16,true><<<cdiv(n,16), 256, 0, stream>>>(bufC, invcnt, Wl2, bufB, Wr2, bl2, bufD, n);
  hipMemsetAsync(stats, 0, 2 * 64 * 4, stream);
  k_bn_stats<64><<<256, 256, 0, stream>>>(bufD, stats, n);
  k_bn_finalize<<<1, 64, 0, stream>>>(stats, g2, be2, 64, 1.0f / n);
  k_bn_apply<64><<<cdiv((long long)n*16, BT), BT, 0, stream>>>(bufD, stats, n);

  // ---- L3: GCN 64->32, BN, LReLU ----
  k_gemm<64,32,32,false><<<cdiv(n,32), 256, 0, stream>>>(bufD, nullptr, W3, nullptr, nullptr, nullptr, bufA, n);
  k_selfloop<32><<<cdiv((long long)n*8, BT), BT, 0, stream>>>(bufA, dinv, b3, bufB, n);
  k_scatter<32,true><<<cdiv((long long)E*8, BT), BT, 0, stream>>>(bufA, dinv, src, dst, bufB, E);
  hipMemsetAsync(stats, 0, 2 * 32 * 4, stream);
  k_bn_stats<32><<<256, 256, 0, stream>>>(bufB, stats, n);
  k_bn_finalize<<<1, 32, 0, stream>>>(stats, g3, be3, 32, 1.0f / n);
  k_bn_apply<32><<<cdiv((long long)n*8, BT), BT, 0, stream>>>(bufB, stats, n);

  // ---- L4: GCN 32->32 (no BN) ----
  k_gemm<32,32,32,false><<<cdiv(n,32), 256, 0, stream>>>(bufB, nullptr, W4, nullptr, nullptr, nullptr, bufA, n);
  k_selfloop<32><<<cdiv((long long)n*8, BT), BT, 0, stream>>>(bufA, dinv, b4, bufC, n);
  k_scatter<32,true><<<cdiv((long long)E*8, BT), BT, 0, stream>>>(bufA, dinv, src, dst, bufC, E);

  // ---- pool + link ----
  hipMemsetAsync(gpool, 0, (size_t)4096 * 32 * 4, stream);
  k_pool<<<cdiv((long long)n*8, BT), BT, 0, stream>>>(bufC, batch, gpool, n);
  k_link<<<cdiv(L, BT), BT, 0, stream>>>(gpool, li0, li1, (float*)d_out, L);
}

// Round 2
// 685.148 us; speedup vs baseline: 5.4990x; 5.4990x over previous
//
#include <hip/hip_runtime.h>
#include <math.h>

#define LEAK 0.01f
#define BNEPS 1e-5f

// ---------------- degree (int) ----------------
__global__ void k_deg(const int* __restrict__ dst, int* __restrict__ deg, int E) {
  int e = blockIdx.x * blockDim.x + threadIdx.x;
  if (e < E) atomicAdd(&deg[dst[e]], 1);
}

__global__ void k_dinv(const int* __restrict__ deg, float* __restrict__ dinv,
                       float* __restrict__ invcnt, int n) {
  int v = blockIdx.x * blockDim.x + threadIdx.x;
  if (v < n) {
    float d = (float)deg[v];
    dinv[v]   = rsqrtf(d + 1.0f);      // GCN: deg includes self-loop
    invcnt[v] = 1.0f / fmaxf(d, 1.0f); // SAGE mean divisor
  }
}

// ---------------- exclusive scan of deg -> rowptr (single block) ----------------
__global__ __launch_bounds__(1024) void k_scan(const int* __restrict__ deg,
                                               int* __restrict__ rowptr, int n) {
  __shared__ int lds[1024];
  const int t = threadIdx.x;
  const int C = (n + 1023) / 1024;
  const int lo = t * C;
  const int hi = min(lo + C, n);
  int s = 0;
  for (int i = lo; i < hi; i++) s += deg[i];
  lds[t] = s;
  __syncthreads();
  for (int ofs = 1; ofs < 1024; ofs <<= 1) {
    int v = (t >= ofs) ? lds[t - ofs] : 0;
    __syncthreads();
    lds[t] += v;
    __syncthreads();
  }
  int p = (t == 0) ? 0 : lds[t - 1];  // exclusive prefix of this chunk
  for (int i = lo; i < hi; i++) { rowptr[i] = p; p += deg[i]; }
  if (t == 1023) rowptr[n] = p;       // total (works even if last chunk empty)
}

// ---------------- CSR fill ----------------
__global__ void k_fill(const int* __restrict__ src, const int* __restrict__ dst,
                       const int* __restrict__ rowptr, int* __restrict__ cursor,
                       int* __restrict__ eidx, int E) {
  int e = blockIdx.x * blockDim.x + threadIdx.x;
  if (e >= E) return;
  int d = dst[e];
  int pos = atomicAdd(&cursor[d], 1);
  eidx[rowptr[d] + pos] = src[e];
}

// ---------------- CSR gather aggregation (one wave per node) ----------------
// GCN:  out[v] = bias + dinv[v] * sum_e dinv[s] H[s] + dinv[v]^2 * H[v]
// SAGE: out[v] = invcnt[v] * sum_e H[s]
template<int F, bool GCN>
__global__ __launch_bounds__(256) void k_gather(
    const float* __restrict__ H, const float* __restrict__ scale,
    const int* __restrict__ rowptr, const int* __restrict__ eidx,
    const float* __restrict__ bias, float* __restrict__ out, int n) {
  constexpr int COLS = F / 4;       // float4 columns per row
  constexpr int EPI  = 64 / COLS;   // edges processed per iteration
  const int wave = threadIdx.x >> 6;
  const int v = blockIdx.x * 4 + wave;
  if (v >= n) return;
  const int lane = threadIdx.x & 63;
  const int col  = lane % COLS;
  const int eo   = lane / COLS;

  const int lo = rowptr[v], hi = rowptr[v + 1];
  float4 acc = {0.f, 0.f, 0.f, 0.f};
  for (int i = lo + eo; i < hi; i += EPI) {
    int s = eidx[i];
    float4 h = *(const float4*)&H[(long long)s * F + col * 4];
    if constexpr (GCN) {
      float w = scale[s];  // dinv[s]
      acc.x = fmaf(h.x, w, acc.x); acc.y = fmaf(h.y, w, acc.y);
      acc.z = fmaf(h.z, w, acc.z); acc.w = fmaf(h.w, w, acc.w);
    } else {
      acc.x += h.x; acc.y += h.y; acc.z += h.z; acc.w += h.w;
    }
  }
  // butterfly-reduce across the edge-offset lanes
#pragma unroll
  for (int m = COLS; m < 64; m <<= 1) {
    acc.x += __shfl_xor(acc.x, m, 64);
    acc.y += __shfl_xor(acc.y, m, 64);
    acc.z += __shfl_xor(acc.z, m, 64);
    acc.w += __shfl_xor(acc.w, m, 64);
  }
  if (eo == 0) {
    float4 o;
    if constexpr (GCN) {
      float dv = scale[v];
      float4 h = *(const float4*)&H[(long long)v * F + col * 4];
      o.x = bias[col * 4 + 0] + dv * acc.x + dv * dv * h.x;
      o.y = bias[col * 4 + 1] + dv * acc.y + dv * dv * h.y;
      o.z = bias[col * 4 + 2] + dv * acc.z + dv * dv * h.z;
      o.w = bias[col * 4 + 3] + dv * acc.w + dv * dv * h.w;
    } else {
      float ic = scale[v];  // invcnt[v]
      o.x = ic * acc.x; o.y = ic * acc.y; o.z = ic * acc.z; o.w = ic * acc.w;
    }
    *(float4*)&out[(long long)v * F + col * 4] = o;
  }
}

// ---------------- GEMM: Y[n,FOUT] = X1[n,K]@Wa (+ X2@Wb) (+bias) -----
template<int K, int FOUT, int ROWS, bool DUAL>
__global__ __launch_bounds__(ROWS*(FOUT/4)) void k_gemm(
    const float* __restrict__ X1, const float* __restrict__ Wa,
    const float* __restrict__ X2, const float* __restrict__ Wb,
    const float* __restrict__ bias,
    float* __restrict__ Y, int n) {
  constexpr int TPR = FOUT / 4;
  constexpr int NT  = ROWS * TPR;
  constexpr int WCAP = 8192;
  constexpr int KC = ((K * FOUT * (DUAL ? 2 : 1)) <= WCAP)
                        ? K : (WCAP / (FOUT * (DUAL ? 2 : 1)));
  __shared__ float sX1[ROWS * K];
  __shared__ float sX2[DUAL ? ROWS * K : 1];
  __shared__ float sWa[KC * FOUT];
  __shared__ float sWb[DUAL ? KC * FOUT : 1];

  const int row0 = blockIdx.x * ROWS;
  for (int i = threadIdx.x; i < ROWS * K; i += NT) {
    int r = i / K, k = i % K;
    int gr = row0 + r;
    float v = 0.f, v2 = 0.f;
    if (gr < n) {
      v = X1[(long long)gr * K + k];
      if constexpr (DUAL) v2 = X2[(long long)gr * K + k];
    }
    sX1[i] = v;
    if constexpr (DUAL) sX2[i] = v2;
  }

  const int r  = threadIdx.x / TPR;
  const int jc = (threadIdx.x % TPR) * 4;
  float ax = 0.f, ay = 0.f, az = 0.f, aw = 0.f;
  for (int k0 = 0; k0 < K; k0 += KC) {
    __syncthreads();
    for (int i = threadIdx.x; i < KC * FOUT; i += NT) {
      int kk = i / FOUT, j = i % FOUT;
      sWa[i] = Wa[(long long)(k0 + kk) * FOUT + j];
      if constexpr (DUAL) sWb[i] = Wb[(long long)(k0 + kk) * FOUT + j];
    }
    __syncthreads();
#pragma unroll 8
    for (int kk = 0; kk < KC; kk++) {
      float xv = sX1[r * K + k0 + kk];
      const float4 w = *(const float4*)&sWa[kk * FOUT + jc];
      ax = fmaf(xv, w.x, ax); ay = fmaf(xv, w.y, ay);
      az = fmaf(xv, w.z, az); aw = fmaf(xv, w.w, aw);
      if constexpr (DUAL) {
        float x2 = sX2[r * K + k0 + kk];
        const float4 wb = *(const float4*)&sWb[kk * FOUT + jc];
        ax = fmaf(x2, wb.x, ax); ay = fmaf(x2, wb.y, ay);
        az = fmaf(x2, wb.z, az); aw = fmaf(x2, wb.w, aw);
      }
    }
  }
  int gr = row0 + r;
  if (gr < n) {
    if (bias) {
      ax += bias[jc + 0]; ay += bias[jc + 1];
      az += bias[jc + 2]; aw += bias[jc + 3];
    }
    float4 o; o.x = ax; o.y = ay; o.z = az; o.w = aw;
    *(float4*)&Y[(long long)gr * FOUT + jc] = o;
  }
}

// ---------------- BatchNorm (training forward, biased var) + LeakyReLU ------
template<int F>
__global__ void k_bn_stats(const float* __restrict__ Y, float* __restrict__ stats, int n) {
  constexpr int RPB = 256 / F;
  int f  = threadIdx.x % F;
  int r0 = threadIdx.x / F;
  float s1 = 0.f, s2 = 0.f;
  for (long long r = (long long)blockIdx.x * RPB + r0; r < n; r += (long long)gridDim.x * RPB) {
    float v = Y[r * F + f];
    s1 += v; s2 += v * v;
  }
  __shared__ float ls1[256], ls2[256];
  ls1[threadIdx.x] = s1; ls2[threadIdx.x] = s2;
  __syncthreads();
  if (r0 == 0) {
#pragma unroll
    for (int i = 1; i < RPB; i++) { s1 += ls1[i * F + f]; s2 += ls2[i * F + f]; }
    atomicAdd(&stats[f], s1);
    atomicAdd(&stats[F + f], s2);
  }
}

__global__ void k_bn_finalize(float* __restrict__ stats, const float* __restrict__ g,
                              const float* __restrict__ be, int F, float invN) {
  int f = blockIdx.x * blockDim.x + threadIdx.x;
  if (f >= F) return;
  float m   = stats[f] * invN;
  float var = stats[F + f] * invN - m * m;
  float sc  = g[f] * rsqrtf(var + BNEPS);
  stats[2 * F + f] = sc;
  stats[3 * F + f] = be[f] - m * sc;
}

template<int F>
__global__ void k_bn_apply(float* __restrict__ Y, const float* __restrict__ stats, int n) {
  constexpr int TPR = F / 4;
  long long idx = (long long)blockIdx.x * blockDim.x + threadIdx.x;
  if (idx >= (long long)n * TPR) return;
  int fc = (int)(idx % TPR) * 4;
  const float4 sc = *(const float4*)&stats[2 * F + fc];
  const float4 sh = *(const float4*)&stats[3 * F + fc];
  float4 y = *(float4*)&Y[idx * 4];
  y.x = fmaf(y.x, sc.x, sh.x); y.x = (y.x >= 0.f) ? y.x : LEAK * y.x;
  y.y = fmaf(y.y, sc.y, sh.y); y.y = (y.y >= 0.f) ? y.y : LEAK * y.y;
  y.z = fmaf(y.z, sc.z, sh.z); y.z = (y.z >= 0.f) ? y.z : LEAK * y.z;
  y.w = fmaf(y.w, sc.w, sh.w); y.w = (y.w >= 0.f) ? y.w : LEAK * y.w;
  *(float4*)&Y[idx * 4] = y;
}

// ---------------- pooling + link prediction ----------------
__global__ void k_pool(const float* __restrict__ A, const int* __restrict__ batch,
                       float* __restrict__ g, int n) {
  long long idx = (long long)blockIdx.x * blockDim.x + threadIdx.x;
  if (idx >= (long long)n * 8) return;
  int v  = (int)(idx / 8);
  int fc = (int)(idx % 8) * 4;
  int b  = batch[v];
  const float4 a = *(const float4*)&A[(long long)v * 32 + fc];
  float* out = &g[(long long)b * 32 + fc];
  atomicAdd(out + 0, a.x);
  atomicAdd(out + 1, a.y);
  atomicAdd(out + 2, a.z);
  atomicAdd(out + 3, a.w);
}

__global__ void k_link(const float* __restrict__ g, const int* __restrict__ li0,
                       const int* __restrict__ li1, float* __restrict__ out, int L) {
  int i = blockIdx.x * blockDim.x + threadIdx.x;
  if (i >= L) return;
  const float* a = g + (long long)li0[i] * 32;
  const float* b = g + (long long)li1[i] * 32;
  float s = 0.f;
#pragma unroll
  for (int f = 0; f < 32; f++) s = fmaf(a[f], b[f], s);
  out[i] = 1.0f / (1.0f + expf(-s));
}

// ---------------- launch ----------------
extern "C" void kernel_launch(void* const* d_in, const int* in_sizes, int n_in,
                              void* d_out, int out_size, void* d_ws, size_t ws_size,
                              hipStream_t stream) {
  const float* x   = (const float*)d_in[0];
  const int* ei    = (const int*)d_in[1];
  const int* batch = (const int*)d_in[2];
  const int* li    = (const int*)d_in[3];
  // d_in[4] = num_graphs (device scalar; G=1000 — pool buffer padded to 4096)
  const float* W1  = (const float*)d_in[5];
  const float* b1  = (const float*)d_in[6];
  const float* g1  = (const float*)d_in[7];
  const float* be1 = (const float*)d_in[8];
  const float* Wl2 = (const float*)d_in[9];
  const float* bl2 = (const float*)d_in[10];
  const float* Wr2 = (const float*)d_in[11];
  const float* g2  = (const float*)d_in[12];
  const float* be2 = (const float*)d_in[13];
  const float* W3  = (const float*)d_in[14];
  const float* b3  = (const float*)d_in[15];
  const float* g3  = (const float*)d_in[16];
  const float* be3 = (const float*)d_in[17];
  const float* W4  = (const float*)d_in[18];
  const float* b4  = (const float*)d_in[19];

  const int n = in_sizes[0] / 128;   // 50000
  const int E = in_sizes[1] / 2;     // 800000
  const int L = in_sizes[3] / 2;     // 1000
  const int* src = ei;
  const int* dst = ei + E;
  const int* li0 = li;
  const int* li1 = li + L;

  char* base = (char*)d_ws;
  size_t off = 0;
  auto alloc = [&](size_t bytes) -> void* {
    void* p = (void*)(base + off);
    off = (off + bytes + 255) & ~(size_t)255;
    return p;
  };
  int*   deg    = (int*)alloc((size_t)n * 4);
  int*   rowptr = (int*)alloc((size_t)(n + 1) * 4);
  int*   cursor = (int*)alloc((size_t)n * 4);
  int*   eidx   = (int*)alloc((size_t)E * 4);
  float* dinv   = (float*)alloc((size_t)n * 4);
  float* invcnt = (float*)alloc((size_t)n * 4);
  float* stats  = (float*)alloc(512 * 4);
  float* gpool  = (float*)alloc((size_t)4096 * 32 * 4);
  float* bufA   = (float*)alloc((size_t)n * 128 * 4);  // h1 / h3 / h4
  float* bufB   = (float*)alloc((size_t)n * 128 * 4);  // a1 / a3
  float* bufC   = (float*)alloc((size_t)n * 128 * 4);  // agg2 / a4
  float* bufD   = (float*)alloc((size_t)n * 64 * 4);   // h2
  (void)ws_size; (void)n_in; (void)out_size;

  const int BT = 256;
  auto cdiv = [](long long a, long long b) { return (int)((a + b - 1) / b); };
  const int GB = cdiv(n, 4);  // gather grid: one wave per node, 4 waves/block

  // ---- CSR build ----
  hipMemsetAsync(deg, 0, (size_t)n * 4, stream);
  hipMemsetAsync(cursor, 0, (size_t)n * 4, stream);
  k_deg<<<cdiv(E, BT), BT, 0, stream>>>(dst, deg, E);
  k_scan<<<1, 1024, 0, stream>>>(deg, rowptr, n);
  k_dinv<<<cdiv(n, BT), BT, 0, stream>>>(deg, dinv, invcnt, n);
  k_fill<<<cdiv(E, BT), BT, 0, stream>>>(src, dst, rowptr, cursor, eidx, E);

  // ---- L1: GCN 128->128, BN, LReLU ----
  k_gemm<128,128,8,false><<<cdiv(n,8), 256, 0, stream>>>(x, W1, nullptr, nullptr, nullptr, bufA, n);
  k_gather<128,true><<<GB, 256, 0, stream>>>(bufA, dinv, rowptr, eidx, b1, bufB, n);
  hipMemsetAsync(stats, 0, 2 * 128 * 4, stream);
  k_bn_stats<128><<<256, 256, 0, stream>>>(bufB, stats, n);
  k_bn_finalize<<<1, 128, 0, stream>>>(stats, g1, be1, 128, 1.0f / n);
  k_bn_apply<128><<<cdiv((long long)n*32, BT), BT, 0, stream>>>(bufB, stats, n);

  // ---- L2: SAGE 128->64, BN, LReLU ----
  k_gather<128,false><<<GB, 256, 0, stream>>>(bufB, invcnt, rowptr, eidx, nullptr, bufC, n);
  k_gemm<128,64,16,true><<<cdiv(n,16), 256, 0, stream>>>(bufC, Wl2, bufB, Wr2, bl2, bufD, n);
  hipMemsetAsync(stats, 0, 2 * 64 * 4, stream);
  k_bn_stats<64><<<256, 256, 0, stream>>>(bufD, stats, n);
  k_bn_finalize<<<1, 64, 0, stream>>>(stats, g2, be2, 64, 1.0f / n);
  k_bn_apply<64><<<cdiv((long long)n*16, BT), BT, 0, stream>>>(bufD, stats, n);

  // ---- L3: GCN 64->32, BN, LReLU ----
  k_gemm<64,32,32,false><<<cdiv(n,32), 256, 0, stream>>>(bufD, W3, nullptr, nullptr, nullptr, bufA, n);
  k_gather<32,true><<<GB, 256, 0, stream>>>(bufA, dinv, rowptr, eidx, b3, bufB, n);
  hipMemsetAsync(stats, 0, 2 * 32 * 4, stream);
  k_bn_stats<32><<<256, 256, 0, stream>>>(bufB, stats, n);
  k_bn_finalize<<<1, 32, 0, stream>>>(stats, g3, be3, 32, 1.0f / n);
  k_bn_apply<32><<<cdiv((long long)n*8, BT), BT, 0, stream>>>(bufB, stats, n);

  // ---- L4: GCN 32->32 (no BN) ----
  k_gemm<32,32,32,false><<<cdiv(n,32), 256, 0, stream>>>(bufB, W4, nullptr, nullptr, nullptr, bufA, n);
  k_gather<32,true><<<GB, 256, 0, stream>>>(bufA, dinv, rowptr, eidx, b4, bufC, n);

  // ---- pool + link ----
  hipMemsetAsync(gpool, 0, (size_t)4096 * 32 * 4, stream);
  k_pool<<<cdiv((long long)n*8, BT), BT, 0, stream>>>(bufC, batch, gpool, n);
  k_link<<<cdiv(L, BT), BT, 0, stream>>>(gpool, li0, li1, (float*)d_out, L);
}

// Round 3
// 643.214 us; speedup vs baseline: 5.8575x; 1.0652x over previous
//
#include <hip/hip_runtime.h>
#include <math.h>

#define LEAK 0.01f
#define BNEPS 1e-5f

// ---------------- degree (int) ----------------
__global__ void k_deg(const int* __restrict__ dst, int* __restrict__ deg, int E) {
  int e = blockIdx.x * blockDim.x + threadIdx.x;
  if (e < E) atomicAdd(&deg[dst[e]], 1);
}

// ---------------- hierarchical exclusive scan of deg -> rowptr ----------------
// phase 1: per-block (256-elem chunk) sums
__global__ __launch_bounds__(256) void k_scan1(const int* __restrict__ deg,
                                               int* __restrict__ bsum, int n) {
  int i = blockIdx.x * 256 + threadIdx.x;
  int v = (i < n) ? deg[i] : 0;
  // wave reduce
#pragma unroll
  for (int m = 1; m < 64; m <<= 1) v += __shfl_xor(v, m, 64);
  __shared__ int ws[4];
  if ((threadIdx.x & 63) == 0) ws[threadIdx.x >> 6] = v;
  __syncthreads();
  if (threadIdx.x == 0) bsum[blockIdx.x] = ws[0] + ws[1] + ws[2] + ws[3];
}

// phase 2: single block scans the NB block sums (NB <= 1024) -> exclusive boff
__global__ __launch_bounds__(1024) void k_scan2(const int* __restrict__ bsum,
                                                int* __restrict__ boff,
                                                int* __restrict__ rowptr,
                                                int NB, int n) {
  __shared__ int lds[1024];
  int t = threadIdx.x;
  int v = (t < NB) ? bsum[t] : 0;
  lds[t] = v;
  __syncthreads();
  for (int ofs = 1; ofs < 1024; ofs <<= 1) {
    int u = (t >= ofs) ? lds[t - ofs] : 0;
    __syncthreads();
    lds[t] += u;
    __syncthreads();
  }
  if (t < NB) boff[t] = lds[t] - v;   // exclusive
  if (t == 1023) rowptr[n] = lds[1023]; // total = E
}

// phase 3: per-chunk exclusive scan + block offset; also dinv/invcnt
__global__ __launch_bounds__(256) void k_scan3(const int* __restrict__ deg,
                                               const int* __restrict__ boff,
                                               int* __restrict__ rowptr,
                                               float* __restrict__ dinv,
                                               float* __restrict__ invcnt, int n) {
  __shared__ int lds[256];
  int t = threadIdx.x;
  int i = blockIdx.x * 256 + t;
  int v = (i < n) ? deg[i] : 0;
  lds[t] = v;
  __syncthreads();
  for (int ofs = 1; ofs < 256; ofs <<= 1) {
    int u = (t >= ofs) ? lds[t - ofs] : 0;
    __syncthreads();
    lds[t] += u;
    __syncthreads();
  }
  if (i < n) {
    rowptr[i] = boff[blockIdx.x] + lds[t] - v;  // exclusive
    float d = (float)v;
    dinv[i]   = rsqrtf(d + 1.0f);       // GCN: deg includes self-loop
    invcnt[i] = 1.0f / fmaxf(d, 1.0f);  // SAGE mean divisor
  }
}

// ---------------- CSR fill ----------------
__global__ void k_fill(const int* __restrict__ src, const int* __restrict__ dst,
                       const int* __restrict__ rowptr, int* __restrict__ cursor,
                       int* __restrict__ eidx, int E) {
  int e = blockIdx.x * blockDim.x + threadIdx.x;
  if (e >= E) return;
  int d = dst[e];
  int pos = atomicAdd(&cursor[d], 1);
  eidx[rowptr[d] + pos] = src[e];
}

// ---------------- CSR gather aggregation (one wave per node) ----------------
// GCN:  out[v] = bias + dinv[v] * sum_e dinv[s] H[s] + dinv[v]^2 * H[v]
// SAGE: out[v] = invcnt[v] * sum_e H[s]
template<int F, bool GCN>
__global__ __launch_bounds__(256) void k_gather(
    const float* __restrict__ H, const float* __restrict__ scale,
    const int* __restrict__ rowptr, const int* __restrict__ eidx,
    const float* __restrict__ bias, float* __restrict__ out, int n) {
  constexpr int COLS = F / 4;       // float4 columns per row
  constexpr int EPI  = 64 / COLS;   // edges processed per iteration
  const int wave = threadIdx.x >> 6;
  const int v = blockIdx.x * 4 + wave;
  if (v >= n) return;
  const int lane = threadIdx.x & 63;
  const int col  = lane % COLS;
  const int eo   = lane / COLS;

  const int lo = rowptr[v], hi = rowptr[v + 1];
  float4 acc = {0.f, 0.f, 0.f, 0.f};
  for (int i = lo + eo; i < hi; i += EPI) {
    int s = eidx[i];
    float4 h = *(const float4*)&H[(long long)s * F + col * 4];
    if constexpr (GCN) {
      float w = scale[s];  // dinv[s]
      acc.x = fmaf(h.x, w, acc.x); acc.y = fmaf(h.y, w, acc.y);
      acc.z = fmaf(h.z, w, acc.z); acc.w = fmaf(h.w, w, acc.w);
    } else {
      acc.x += h.x; acc.y += h.y; acc.z += h.z; acc.w += h.w;
    }
  }
  // butterfly-reduce across the edge-offset lanes
#pragma unroll
  for (int m = COLS; m < 64; m <<= 1) {
    acc.x += __shfl_xor(acc.x, m, 64);
    acc.y += __shfl_xor(acc.y, m, 64);
    acc.z += __shfl_xor(acc.z, m, 64);
    acc.w += __shfl_xor(acc.w, m, 64);
  }
  if (eo == 0) {
    float4 o;
    if constexpr (GCN) {
      float dv = scale[v];
      float4 h = *(const float4*)&H[(long long)v * F + col * 4];
      o.x = bias[col * 4 + 0] + dv * acc.x + dv * dv * h.x;
      o.y = bias[col * 4 + 1] + dv * acc.y + dv * dv * h.y;
      o.z = bias[col * 4 + 2] + dv * acc.z + dv * dv * h.z;
      o.w = bias[col * 4 + 3] + dv * acc.w + dv * dv * h.w;
    } else {
      float ic = scale[v];  // invcnt[v]
      o.x = ic * acc.x; o.y = ic * acc.y; o.z = ic * acc.z; o.w = ic * acc.w;
    }
    *(float4*)&out[(long long)v * F + col * 4] = o;
  }
}

// ---------------- GEMM: Y[n,FOUT] = X1[n,K]@Wa (+ X2@Wb) (+bias) -----
template<int K, int FOUT, int ROWS, bool DUAL>
__global__ __launch_bounds__(ROWS*(FOUT/4)) void k_gemm(
    const float* __restrict__ X1, const float* __restrict__ Wa,
    const float* __restrict__ X2, const float* __restrict__ Wb,
    const float* __restrict__ bias,
    float* __restrict__ Y, int n) {
  constexpr int TPR = FOUT / 4;
  constexpr int NT  = ROWS * TPR;
  constexpr int WCAP = 8192;
  constexpr int KC = ((K * FOUT * (DUAL ? 2 : 1)) <= WCAP)
                        ? K : (WCAP / (FOUT * (DUAL ? 2 : 1)));
  __shared__ float sX1[ROWS * K];
  __shared__ float sX2[DUAL ? ROWS * K : 1];
  __shared__ float sWa[KC * FOUT];
  __shared__ float sWb[DUAL ? KC * FOUT : 1];

  const int row0 = blockIdx.x * ROWS;
  for (int i = threadIdx.x; i < ROWS * K; i += NT) {
    int r = i / K, k = i % K;
    int gr = row0 + r;
    float v = 0.f, v2 = 0.f;
    if (gr < n) {
      v = X1[(long long)gr * K + k];
      if constexpr (DUAL) v2 = X2[(long long)gr * K + k];
    }
    sX1[i] = v;
    if constexpr (DUAL) sX2[i] = v2;
  }

  const int r  = threadIdx.x / TPR;
  const int jc = (threadIdx.x % TPR) * 4;
  float ax = 0.f, ay = 0.f, az = 0.f, aw = 0.f;
  for (int k0 = 0; k0 < K; k0 += KC) {
    __syncthreads();
    for (int i = threadIdx.x; i < KC * FOUT; i += NT) {
      int kk = i / FOUT, j = i % FOUT;
      sWa[i] = Wa[(long long)(k0 + kk) * FOUT + j];
      if constexpr (DUAL) sWb[i] = Wb[(long long)(k0 + kk) * FOUT + j];
    }
    __syncthreads();
#pragma unroll 8
    for (int kk = 0; kk < KC; kk++) {
      float xv = sX1[r * K + k0 + kk];
      const float4 w = *(const float4*)&sWa[kk * FOUT + jc];
      ax = fmaf(xv, w.x, ax); ay = fmaf(xv, w.y, ay);
      az = fmaf(xv, w.z, az); aw = fmaf(xv, w.w, aw);
      if constexpr (DUAL) {
        float x2 = sX2[r * K + k0 + kk];
        const float4 wb = *(const float4*)&sWb[kk * FOUT + jc];
        ax = fmaf(x2, wb.x, ax); ay = fmaf(x2, wb.y, ay);
        az = fmaf(x2, wb.z, az); aw = fmaf(x2, wb.w, aw);
      }
    }
  }
  int gr = row0 + r;
  if (gr < n) {
    if (bias) {
      ax += bias[jc + 0]; ay += bias[jc + 1];
      az += bias[jc + 2]; aw += bias[jc + 3];
    }
    float4 o; o.x = ax; o.y = ay; o.z = az; o.w = aw;
    *(float4*)&Y[(long long)gr * FOUT + jc] = o;
  }
}

// ---------------- BatchNorm (training forward, biased var) + LeakyReLU ------
// stats: 256 blocks write partial sums (no atomics, no memset needed)
template<int F>
__global__ __launch_bounds__(256) void k_bn_stats(const float* __restrict__ Y,
                                                  float* __restrict__ partials, int n) {
  constexpr int RPB = 256 / F;
  int f  = threadIdx.x % F;
  int r0 = threadIdx.x / F;
  float s1 = 0.f, s2 = 0.f;
  for (long long r = (long long)blockIdx.x * RPB + r0; r < n; r += 256LL * RPB) {
    float v = Y[r * F + f];
    s1 += v; s2 += v * v;
  }
  __shared__ float ls1[256], ls2[256];
  ls1[threadIdx.x] = s1; ls2[threadIdx.x] = s2;
  __syncthreads();
  if (r0 == 0) {
#pragma unroll
    for (int i = 1; i < RPB; i++) { s1 += ls1[i * F + f]; s2 += ls2[i * F + f]; }
    partials[blockIdx.x * 2 * F + f]     = s1;
    partials[blockIdx.x * 2 * F + F + f] = s2;
  }
}

// reduce partials -> scale (stats[0..F)) and shift (stats[F..2F))
__global__ void k_bn_finalize(const float* __restrict__ partials, float* __restrict__ stats,
                              const float* __restrict__ g, const float* __restrict__ be,
                              int F, float invN) {
  int f = threadIdx.x;
  if (f >= F) return;
  float s1 = 0.f, s2 = 0.f;
  for (int b = 0; b < 256; b++) {
    s1 += partials[b * 2 * F + f];
    s2 += partials[b * 2 * F + F + f];
  }
  float m   = s1 * invN;
  float var = s2 * invN - m * m;
  float sc  = g[f] * rsqrtf(var + BNEPS);
  stats[f]     = sc;
  stats[F + f] = be[f] - m * sc;
}

template<int F>
__global__ void k_bn_apply(float* __restrict__ Y, const float* __restrict__ stats, int n) {
  constexpr int TPR = F / 4;
  long long idx = (long long)blockIdx.x * blockDim.x + threadIdx.x;
  if (idx >= (long long)n * TPR) return;
  int fc = (int)(idx % TPR) * 4;
  const float4 sc = *(const float4*)&stats[fc];
  const float4 sh = *(const float4*)&stats[F + fc];
  float4 y = *(float4*)&Y[idx * 4];
  y.x = fmaf(y.x, sc.x, sh.x); y.x = (y.x >= 0.f) ? y.x : LEAK * y.x;
  y.y = fmaf(y.y, sc.y, sh.y); y.y = (y.y >= 0.f) ? y.y : LEAK * y.y;
  y.z = fmaf(y.z, sc.z, sh.z); y.z = (y.z >= 0.f) ? y.z : LEAK * y.z;
  y.w = fmaf(y.w, sc.w, sh.w); y.w = (y.w >= 0.f) ? y.w : LEAK * y.w;
  *(float4*)&Y[idx * 4] = y;
}

// ---------------- pooling + link prediction ----------------
__global__ void k_pool(const float* __restrict__ A, const int* __restrict__ batch,
                       float* __restrict__ g, int n) {
  long long idx = (long long)blockIdx.x * blockDim.x + threadIdx.x;
  if (idx >= (long long)n * 8) return;
  int v  = (int)(idx / 8);
  int fc = (int)(idx % 8) * 4;
  int b  = batch[v];
  const float4 a = *(const float4*)&A[(long long)v * 32 + fc];
  float* out = &g[(long long)b * 32 + fc];
  atomicAdd(out + 0, a.x);
  atomicAdd(out + 1, a.y);
  atomicAdd(out + 2, a.z);
  atomicAdd(out + 3, a.w);
}

__global__ void k_link(const float* __restrict__ g, const int* __restrict__ li0,
                       const int* __restrict__ li1, float* __restrict__ out, int L) {
  int i = blockIdx.x * blockDim.x + threadIdx.x;
  if (i >= L) return;
  const float* a = g + (long long)li0[i] * 32;
  const float* b = g + (long long)li1[i] * 32;
  float s = 0.f;
#pragma unroll
  for (int f = 0; f < 32; f++) s = fmaf(a[f], b[f], s);
  out[i] = 1.0f / (1.0f + expf(-s));
}

// ---------------- launch ----------------
extern "C" void kernel_launch(void* const* d_in, const int* in_sizes, int n_in,
                              void* d_out, int out_size, void* d_ws, size_t ws_size,
                              hipStream_t stream) {
  const float* x   = (const float*)d_in[0];
  const int* ei    = (const int*)d_in[1];
  const int* batch = (const int*)d_in[2];
  const int* li    = (const int*)d_in[3];
  // d_in[4] = num_graphs (device scalar; G=1000 — pool buffer padded to 4096)
  const float* W1  = (const float*)d_in[5];
  const float* b1  = (const float*)d_in[6];
  const float* g1  = (const float*)d_in[7];
  const float* be1 = (const float*)d_in[8];
  const float* Wl2 = (const float*)d_in[9];
  const float* bl2 = (const float*)d_in[10];
  const float* Wr2 = (const float*)d_in[11];
  const float* g2  = (const float*)d_in[12];
  const float* be2 = (const float*)d_in[13];
  const float* W3  = (const float*)d_in[14];
  const float* b3  = (const float*)d_in[15];
  const float* g3  = (const float*)d_in[16];
  const float* be3 = (const float*)d_in[17];
  const float* W4  = (const float*)d_in[18];
  const float* b4  = (const float*)d_in[19];

  const int n = in_sizes[0] / 128;   // 50000
  const int E = in_sizes[1] / 2;     // 800000
  const int L = in_sizes[3] / 2;     // 1000
  const int* src = ei;
  const int* dst = ei + E;
  const int* li0 = li;
  const int* li1 = li + L;

  char* base = (char*)d_ws;
  size_t off = 0;
  auto alloc = [&](size_t bytes) -> void* {
    void* p = (void*)(base + off);
    off = (off + bytes + 255) & ~(size_t)255;
    return p;
  };
  int*   deg    = (int*)alloc((size_t)n * 4);
  int*   rowptr = (int*)alloc((size_t)(n + 1) * 4);
  int*   cursor = (int*)alloc((size_t)n * 4);
  int*   eidx   = (int*)alloc((size_t)E * 4);
  int*   bsum   = (int*)alloc((size_t)1024 * 4);
  int*   boff   = (int*)alloc((size_t)1024 * 4);
  float* dinv   = (float*)alloc((size_t)n * 4);
  float* invcnt = (float*)alloc((size_t)n * 4);
  float* stats  = (float*)alloc(512 * 4);
  float* partials = (float*)alloc((size_t)256 * 256 * 4);
  float* gpool  = (float*)alloc((size_t)4096 * 32 * 4);
  float* bufA   = (float*)alloc((size_t)n * 128 * 4);  // h1 / h3 / h4
  float* bufB   = (float*)alloc((size_t)n * 128 * 4);  // a1 / a3
  float* bufC   = (float*)alloc((size_t)n * 128 * 4);  // agg2 / a4
  float* bufD   = (float*)alloc((size_t)n * 64 * 4);   // h2
  (void)ws_size; (void)n_in; (void)out_size;

  const int BT = 256;
  auto cdiv = [](long long a, long long b) { return (int)((a + b - 1) / b); };
  const int GB = cdiv(n, 4);       // gather grid: one wave per node, 4 waves/block
  const int NB = cdiv(n, 256);     // scan chunks (196 <= 1024)

  // ---- CSR build ----
  hipMemsetAsync(deg, 0, (size_t)n * 4, stream);
  hipMemsetAsync(cursor, 0, (size_t)n * 4, stream);
  k_deg<<<cdiv(E, BT), BT, 0, stream>>>(dst, deg, E);
  k_scan1<<<NB, 256, 0, stream>>>(deg, bsum, n);
  k_scan2<<<1, 1024, 0, stream>>>(bsum, boff, rowptr, NB, n);
  k_scan3<<<NB, 256, 0, stream>>>(deg, boff, rowptr, dinv, invcnt, n);
  k_fill<<<cdiv(E, BT), BT, 0, stream>>>(src, dst, rowptr, cursor, eidx, E);

  // ---- L1: GCN 128->128, BN, LReLU ----
  k_gemm<128,128,8,false><<<cdiv(n,8), 256, 0, stream>>>(x, W1, nullptr, nullptr, nullptr, bufA, n);
  k_gather<128,true><<<GB, 256, 0, stream>>>(bufA, dinv, rowptr, eidx, b1, bufB, n);
  k_bn_stats<128><<<256, 256, 0, stream>>>(bufB, partials, n);
  k_bn_finalize<<<1, 128, 0, stream>>>(partials, stats, g1, be1, 128, 1.0f / n);
  k_bn_apply<128><<<cdiv((long long)n*32, BT), BT, 0, stream>>>(bufB, stats, n);

  // ---- L2: SAGE 128->64, BN, LReLU ----
  k_gather<128,false><<<GB, 256, 0, stream>>>(bufB, invcnt, rowptr, eidx, nullptr, bufC, n);
  k_gemm<128,64,16,true><<<cdiv(n,16), 256, 0, stream>>>(bufC, Wl2, bufB, Wr2, bl2, bufD, n);
  k_bn_stats<64><<<256, 256, 0, stream>>>(bufD, partials, n);
  k_bn_finalize<<<1, 64, 0, stream>>>(partials, stats, g2, be2, 64, 1.0f / n);
  k_bn_apply<64><<<cdiv((long long)n*16, BT), BT, 0, stream>>>(bufD, stats, n);

  // ---- L3: GCN 64->32, BN, LReLU ----
  k_gemm<64,32,32,false><<<cdiv(n,32), 256, 0, stream>>>(bufD, W3, nullptr, nullptr, nullptr, bufA, n);
  k_gather<32,true><<<GB, 256, 0, stream>>>(bufA, dinv, rowptr, eidx, b3, bufB, n);
  k_bn_stats<32><<<256, 256, 0, stream>>>(bufB, partials, n);
  k_bn_finalize<<<1, 32, 0, stream>>>(partials, stats, g3, be3, 32, 1.0f / n);
  k_bn_apply<32><<<cdiv((long long)n*8, BT), BT, 0, stream>>>(bufB, stats, n);

  // ---- L4: GCN 32->32 (no BN) ----
  k_gemm<32,32,32,false><<<cdiv(n,32), 256, 0, stream>>>(bufB, W4, nullptr, nullptr, nullptr, bufA, n);
  k_gather<32,true><<<GB, 256, 0, stream>>>(bufA, dinv, rowptr, eidx, b4, bufC, n);

  // ---- pool + link ----
  hipMemsetAsync(gpool, 0, (size_t)4096 * 32 * 4, stream);
  k_pool<<<cdiv((long long)n*8, BT), BT, 0, stream>>>(bufC, batch, gpool, n);
  k_link<<<cdiv(L, BT), BT, 0, stream>>>(gpool, li0, li1, (float*)d_out, L);
}

// Round 4
// 552.789 us; speedup vs baseline: 6.8157x; 1.1636x over previous
//
#include <hip/hip_runtime.h>
#include <math.h>

#define LEAK 0.01f
#define BNEPS 1e-5f

// ---------------- bf16 helpers ----------------
__device__ inline unsigned bfpack(float a, float b) {  // two f32 -> packed bf16 (RNE)
  unsigned ua = __float_as_uint(a);
  unsigned ub = __float_as_uint(b);
  unsigned ra = (ua + 0x7fffu + ((ua >> 16) & 1u)) >> 16;
  unsigned rb = (ub + 0x7fffu + ((ub >> 16) & 1u)) & 0xffff0000u;
  return ra | rb;
}
__device__ inline float2 bfunpack(unsigned u) {
  float2 r;
  r.x = __uint_as_float(u << 16);
  r.y = __uint_as_float(u & 0xffff0000u);
  return r;
}

// ---------------- degree (int) ----------------
__global__ void k_deg(const int* __restrict__ dst, int* __restrict__ deg, int E) {
  int e = blockIdx.x * blockDim.x + threadIdx.x;
  if (e < E) atomicAdd(&deg[dst[e]], 1);
}

// ---------------- hierarchical exclusive scan of deg -> rowptr ----------------
__global__ __launch_bounds__(256) void k_scan1(const int* __restrict__ deg,
                                               int* __restrict__ bsum, int n) {
  int i = blockIdx.x * 256 + threadIdx.x;
  int v = (i < n) ? deg[i] : 0;
#pragma unroll
  for (int m = 1; m < 64; m <<= 1) v += __shfl_xor(v, m, 64);
  __shared__ int ws[4];
  if ((threadIdx.x & 63) == 0) ws[threadIdx.x >> 6] = v;
  __syncthreads();
  if (threadIdx.x == 0) bsum[blockIdx.x] = ws[0] + ws[1] + ws[2] + ws[3];
}

__global__ __launch_bounds__(1024) void k_scan2(const int* __restrict__ bsum,
                                                int* __restrict__ boff,
                                                int* __restrict__ rowptr,
                                                int NB, int n) {
  __shared__ int lds[1024];
  int t = threadIdx.x;
  int v = (t < NB) ? bsum[t] : 0;
  lds[t] = v;
  __syncthreads();
  for (int ofs = 1; ofs < 1024; ofs <<= 1) {
    int u = (t >= ofs) ? lds[t - ofs] : 0;
    __syncthreads();
    lds[t] += u;
    __syncthreads();
  }
  if (t < NB) boff[t] = lds[t] - v;
  if (t == 1023) rowptr[n] = lds[1023];
}

__global__ __launch_bounds__(256) void k_scan3(const int* __restrict__ deg,
                                               const int* __restrict__ boff,
                                               int* __restrict__ rowptr,
                                               float* __restrict__ dinv,
                                               float* __restrict__ invcnt, int n) {
  __shared__ int lds[256];
  int t = threadIdx.x;
  int i = blockIdx.x * 256 + t;
  int v = (i < n) ? deg[i] : 0;
  lds[t] = v;
  __syncthreads();
  for (int ofs = 1; ofs < 256; ofs <<= 1) {
    int u = (t >= ofs) ? lds[t - ofs] : 0;
    __syncthreads();
    lds[t] += u;
    __syncthreads();
  }
  if (i < n) {
    rowptr[i] = boff[blockIdx.x] + lds[t] - v;
    float d = (float)v;
    dinv[i]   = rsqrtf(d + 1.0f);
    invcnt[i] = 1.0f / fmaxf(d, 1.0f);
  }
}

// ---------------- CSR fill ----------------
__global__ void k_fill(const int* __restrict__ src, const int* __restrict__ dst,
                       const int* __restrict__ rowptr, int* __restrict__ cursor,
                       int* __restrict__ eidx, int E) {
  int e = blockIdx.x * blockDim.x + threadIdx.x;
  if (e >= E) return;
  int d = dst[e];
  int pos = atomicAdd(&cursor[d], 1);
  eidx[rowptr[d] + pos] = src[e];
}

// ---------------- CSR gather aggregation over bf16 rows (one wave/node) ------
// GCN:  Hs holds dinv[r]*h[r] (prescaled). out[v] = bias + dinv[v]*(sum_e Hs[s] + Hs[v])
// SAGE: Hs holds h[r].           out[v] = invcnt[v]*sum_e Hs[s]
template<int F, bool GCN>
__global__ __launch_bounds__(256) void k_gather(
    const unsigned short* __restrict__ Hs, const float* __restrict__ scale,
    const int* __restrict__ rowptr, const int* __restrict__ eidx,
    const float* __restrict__ bias, float* __restrict__ out, int n) {
  constexpr int COLS = F / 8;       // lanes per edge (8 bf16 = 16 B each)
  constexpr int EPI  = 64 / COLS;   // edges per iteration
  const int v = blockIdx.x * 4 + (threadIdx.x >> 6);
  if (v >= n) return;
  const int lane = threadIdx.x & 63;
  const int col  = lane % COLS;
  const int eo   = lane / COLS;

  const int lo = rowptr[v], hi = rowptr[v + 1];
  float a[8] = {0.f,0.f,0.f,0.f,0.f,0.f,0.f,0.f};
  for (int i = lo + eo; i < hi; i += EPI) {
    int s = eidx[i];
    uint4 hv = *(const uint4*)&Hs[(long long)s * F + col * 8];
    float2 p0 = bfunpack(hv.x), p1 = bfunpack(hv.y);
    float2 p2 = bfunpack(hv.z), p3 = bfunpack(hv.w);
    a[0]+=p0.x; a[1]+=p0.y; a[2]+=p1.x; a[3]+=p1.y;
    a[4]+=p2.x; a[5]+=p2.y; a[6]+=p3.x; a[7]+=p3.y;
  }
#pragma unroll
  for (int m = COLS; m < 64; m <<= 1) {
#pragma unroll
    for (int j = 0; j < 8; j++) a[j] += __shfl_xor(a[j], m, 64);
  }
  if (eo == 0) {
    float sv = scale[v];
    float o[8];
    if constexpr (GCN) {
      uint4 hv = *(const uint4*)&Hs[(long long)v * F + col * 8];
      float2 p0 = bfunpack(hv.x), p1 = bfunpack(hv.y);
      float2 p2 = bfunpack(hv.z), p3 = bfunpack(hv.w);
      float h[8] = {p0.x,p0.y,p1.x,p1.y,p2.x,p2.y,p3.x,p3.y};
#pragma unroll
      for (int j = 0; j < 8; j++) o[j] = bias[col * 8 + j] + sv * (a[j] + h[j]);
    } else {
#pragma unroll
      for (int j = 0; j < 8; j++) o[j] = sv * a[j];
    }
    float4 o0 = {o[0],o[1],o[2],o[3]}, o1 = {o[4],o[5],o[6],o[7]};
    *(float4*)&out[(long long)v * F + col * 8]     = o0;
    *(float4*)&out[(long long)v * F + col * 8 + 4] = o1;
  }
}

// ---- GEMM: Y = X1@Wa (+X2@Wb) (+bias); out fp32 or bf16 (opt prescaled) ----
// R rows x 4 cols per thread; 256 threads/block.
template<int K, int FOUT, int KC, int R, bool DUAL, bool BF16OUT>
__global__ __launch_bounds__(256) void k_gemm(
    const float* __restrict__ X1, const float* __restrict__ Wa,
    const float* __restrict__ X2, const float* __restrict__ Wb,
    const float* __restrict__ bias, const float* __restrict__ prescale,
    float* __restrict__ Yf, unsigned short* __restrict__ Yb, int n) {
  constexpr int TPR  = FOUT / 4;
  constexpr int RGN  = 256 / TPR;
  constexpr int ROWS = RGN * R;
  __shared__ float sX1[ROWS * K];
  __shared__ float sX2[DUAL ? ROWS * K : 1];
  __shared__ float sWa[KC * FOUT];
  __shared__ float sWb[DUAL ? KC * FOUT : 1];

  const int row0 = blockIdx.x * ROWS;
  for (int i = threadIdx.x; i < ROWS * K / 4; i += 256) {
    int r = i / (K / 4), k4 = (i % (K / 4)) * 4;
    int gr = row0 + r;
    float4 v = {0,0,0,0}, v2 = {0,0,0,0};
    if (gr < n) {
      v = *(const float4*)&X1[(long long)gr * K + k4];
      if constexpr (DUAL) v2 = *(const float4*)&X2[(long long)gr * K + k4];
    }
    *(float4*)&sX1[r * K + k4] = v;
    if constexpr (DUAL) *(float4*)&sX2[r * K + k4] = v2;
  }

  const int cg = threadIdx.x % TPR;
  const int rg = threadIdx.x / TPR;
  const int jc = cg * 4;
  float4 acc[R];
#pragma unroll
  for (int i = 0; i < R; i++) acc[i] = {0.f,0.f,0.f,0.f};

  for (int k0 = 0; k0 < K; k0 += KC) {
    __syncthreads();
    for (int i = threadIdx.x; i < KC * FOUT / 4; i += 256) {
      int kk = i / (FOUT / 4), j4 = (i % (FOUT / 4)) * 4;
      *(float4*)&sWa[kk * FOUT + j4] = *(const float4*)&Wa[(long long)(k0 + kk) * FOUT + j4];
      if constexpr (DUAL)
        *(float4*)&sWb[kk * FOUT + j4] = *(const float4*)&Wb[(long long)(k0 + kk) * FOUT + j4];
    }
    __syncthreads();
#pragma unroll 8
    for (int kk = 0; kk < KC; kk++) {
      const float4 w = *(const float4*)&sWa[kk * FOUT + jc];
#pragma unroll
      for (int i = 0; i < R; i++) {
        float xv = sX1[(rg * R + i) * K + k0 + kk];
        acc[i].x = fmaf(xv, w.x, acc[i].x); acc[i].y = fmaf(xv, w.y, acc[i].y);
        acc[i].z = fmaf(xv, w.z, acc[i].z); acc[i].w = fmaf(xv, w.w, acc[i].w);
      }
      if constexpr (DUAL) {
        const float4 w2 = *(const float4*)&sWb[kk * FOUT + jc];
#pragma unroll
        for (int i = 0; i < R; i++) {
          float xv = sX2[(rg * R + i) * K + k0 + kk];
          acc[i].x = fmaf(xv, w2.x, acc[i].x); acc[i].y = fmaf(xv, w2.y, acc[i].y);
          acc[i].z = fmaf(xv, w2.z, acc[i].z); acc[i].w = fmaf(xv, w2.w, acc[i].w);
        }
      }
    }
  }
#pragma unroll
  for (int i = 0; i < R; i++) {
    int gr = row0 + rg * R + i;
    if (gr >= n) continue;
    float4 o = acc[i];
    if (bias) { o.x += bias[jc]; o.y += bias[jc+1]; o.z += bias[jc+2]; o.w += bias[jc+3]; }
    if constexpr (BF16OUT) {
      float ps = prescale ? prescale[gr] : 1.0f;
      uint2 u;
      u.x = bfpack(o.x * ps, o.y * ps);
      u.y = bfpack(o.z * ps, o.w * ps);
      *(uint2*)&Yb[(long long)gr * FOUT + jc] = u;
    } else {
      *(float4*)&Yf[(long long)gr * FOUT + jc] = o;
    }
  }
}

// ---------------- BatchNorm (training fwd, biased var) + LeakyReLU ----------
template<int F>
__global__ __launch_bounds__(256) void k_bn_stats(const float* __restrict__ Y,
                                                  float* __restrict__ partials, int n) {
  constexpr int RPB = 256 / F;
  int f  = threadIdx.x % F;
  int r0 = threadIdx.x / F;
  float s1 = 0.f, s2 = 0.f;
  for (long long r = (long long)blockIdx.x * RPB + r0; r < n; r += 256LL * RPB) {
    float v = Y[r * F + f];
    s1 += v; s2 += v * v;
  }
  __shared__ float ls1[256], ls2[256];
  ls1[threadIdx.x] = s1; ls2[threadIdx.x] = s2;
  __syncthreads();
  if (r0 == 0) {
#pragma unroll
    for (int i = 1; i < RPB; i++) { s1 += ls1[i * F + f]; s2 += ls2[i * F + f]; }
    partials[blockIdx.x * 2 * F + f]     = s1;
    partials[blockIdx.x * 2 * F + F + f] = s2;
  }
}

__global__ void k_bn_finalize(const float* __restrict__ partials, float* __restrict__ stats,
                              const float* __restrict__ g, const float* __restrict__ be,
                              int F, float invN) {
  int f = threadIdx.x;
  if (f >= F) return;
  float s1 = 0.f, s2 = 0.f;
  for (int b = 0; b < 256; b++) {
    s1 += partials[b * 2 * F + f];
    s2 += partials[b * 2 * F + F + f];
  }
  float m   = s1 * invN;
  float var = s2 * invN - m * m;
  float sc  = g[f] * rsqrtf(var + BNEPS);
  stats[f]     = sc;
  stats[F + f] = be[f] - m * sc;
}

// fp32 in-place; optionally also a bf16 copy (for the next gather)
template<int F, bool WB>
__global__ void k_bn_apply(float* __restrict__ Y, const float* __restrict__ stats,
                           unsigned short* __restrict__ Yb, int n) {
  constexpr int TPR = F / 4;
  long long idx = (long long)blockIdx.x * blockDim.x + threadIdx.x;
  if (idx >= (long long)n * TPR) return;
  int fc = (int)(idx % TPR) * 4;
  const float4 sc = *(const float4*)&stats[fc];
  const float4 sh = *(const float4*)&stats[F + fc];
  float4 y = *(float4*)&Y[idx * 4];
  y.x = fmaf(y.x, sc.x, sh.x); y.x = (y.x >= 0.f) ? y.x : LEAK * y.x;
  y.y = fmaf(y.y, sc.y, sh.y); y.y = (y.y >= 0.f) ? y.y : LEAK * y.y;
  y.z = fmaf(y.z, sc.z, sh.z); y.z = (y.z >= 0.f) ? y.z : LEAK * y.z;
  y.w = fmaf(y.w, sc.w, sh.w); y.w = (y.w >= 0.f) ? y.w : LEAK * y.w;
  *(float4*)&Y[idx * 4] = y;
  if constexpr (WB) {
    uint2 u;
    u.x = bfpack(y.x, y.y);
    u.y = bfpack(y.z, y.w);
    *(uint2*)&Yb[idx * 4] = u;
  }
}

// ---------------- pooling + link prediction ----------------
__global__ void k_pool(const float* __restrict__ A, const int* __restrict__ batch,
                       float* __restrict__ g, int n) {
  long long idx = (long long)blockIdx.x * blockDim.x + threadIdx.x;
  if (idx >= (long long)n * 8) return;
  int v  = (int)(idx / 8);
  int fc = (int)(idx % 8) * 4;
  int b  = batch[v];
  const float4 a = *(const float4*)&A[(long long)v * 32 + fc];
  float* out = &g[(long long)b * 32 + fc];
  atomicAdd(out + 0, a.x);
  atomicAdd(out + 1, a.y);
  atomicAdd(out + 2, a.z);
  atomicAdd(out + 3, a.w);
}

__global__ void k_link(const float* __restrict__ g, const int* __restrict__ li0,
                       const int* __restrict__ li1, float* __restrict__ out, int L) {
  int i = blockIdx.x * blockDim.x + threadIdx.x;
  if (i >= L) return;
  const float* a = g + (long long)li0[i] * 32;
  const float* b = g + (long long)li1[i] * 32;
  float s = 0.f;
#pragma unroll
  for (int f = 0; f < 32; f++) s = fmaf(a[f], b[f], s);
  out[i] = 1.0f / (1.0f + expf(-s));
}

// ---------------- launch ----------------
extern "C" void kernel_launch(void* const* d_in, const int* in_sizes, int n_in,
                              void* d_out, int out_size, void* d_ws, size_t ws_size,
                              hipStream_t stream) {
  const float* x   = (const float*)d_in[0];
  const int* ei    = (const int*)d_in[1];
  const int* batch = (const int*)d_in[2];
  const int* li    = (const int*)d_in[3];
  const float* W1  = (const float*)d_in[5];
  const float* b1  = (const float*)d_in[6];
  const float* g1  = (const float*)d_in[7];
  const float* be1 = (const float*)d_in[8];
  const float* Wl2 = (const float*)d_in[9];
  const float* bl2 = (const float*)d_in[10];
  const float* Wr2 = (const float*)d_in[11];
  const float* g2  = (const float*)d_in[12];
  const float* be2 = (const float*)d_in[13];
  const float* W3  = (const float*)d_in[14];
  const float* b3  = (const float*)d_in[15];
  const float* g3  = (const float*)d_in[16];
  const float* be3 = (const float*)d_in[17];
  const float* W4  = (const float*)d_in[18];
  const float* b4  = (const float*)d_in[19];

  const int n = in_sizes[0] / 128;   // 50000
  const int E = in_sizes[1] / 2;     // 800000
  const int L = in_sizes[3] / 2;     // 1000
  const int* src = ei;
  const int* dst = ei + E;
  const int* li0 = li;
  const int* li1 = li + L;

  char* base = (char*)d_ws;
  size_t off = 0;
  auto alloc = [&](size_t bytes) -> void* {
    void* p = (void*)(base + off);
    off = (off + bytes + 255) & ~(size_t)255;
    return p;
  };
  int*   deg    = (int*)alloc((size_t)n * 4);
  int*   rowptr = (int*)alloc((size_t)(n + 1) * 4);
  int*   cursor = (int*)alloc((size_t)n * 4);
  int*   eidx   = (int*)alloc((size_t)E * 4);
  int*   bsum   = (int*)alloc((size_t)1024 * 4);
  int*   boff   = (int*)alloc((size_t)1024 * 4);
  float* dinv   = (float*)alloc((size_t)n * 4);
  float* invcnt = (float*)alloc((size_t)n * 4);
  float* stats  = (float*)alloc(512 * 4);
  float* partials = (float*)alloc((size_t)256 * 256 * 4);
  float* gpool  = (float*)alloc((size_t)4096 * 32 * 4);
  unsigned short* h1b  = (unsigned short*)alloc((size_t)n * 128 * 2); // dinv*(x@W1) bf16
  unsigned short* h1pb = (unsigned short*)alloc((size_t)n * 128 * 2); // post-BN h1 bf16
  unsigned short* h3b  = (unsigned short*)alloc((size_t)n * 32 * 2);  // dinv*(h2@W3) bf16
  unsigned short* h4b  = (unsigned short*)alloc((size_t)n * 32 * 2);  // dinv*(h3@W4) bf16
  float* bufB   = (float*)alloc((size_t)n * 128 * 4);  // a1 / h1' (fp32)
  float* bufC   = (float*)alloc((size_t)n * 128 * 4);  // agg2 / a3 / a4
  float* bufD   = (float*)alloc((size_t)n * 64 * 4);   // h2
  (void)ws_size; (void)n_in; (void)out_size;

  const int BT = 256;
  auto cdiv = [](long long a, long long b) { return (int)((a + b - 1) / b); };
  const int GB = cdiv(n, 4);
  const int NB = cdiv(n, 256);

  // ---- CSR build ----
  hipMemsetAsync(deg, 0, (size_t)n * 4, stream);
  hipMemsetAsync(cursor, 0, (size_t)n * 4, stream);
  k_deg<<<cdiv(E, BT), BT, 0, stream>>>(dst, deg, E);
  k_scan1<<<NB, 256, 0, stream>>>(deg, bsum, n);
  k_scan2<<<1, 1024, 0, stream>>>(bsum, boff, rowptr, NB, n);
  k_scan3<<<NB, 256, 0, stream>>>(deg, boff, rowptr, dinv, invcnt, n);
  k_fill<<<cdiv(E, BT), BT, 0, stream>>>(src, dst, rowptr, cursor, eidx, E);

  // ---- L1: GCN 128->128, BN, LReLU ----
  // h1b = dinv * (x@W1) in bf16 (prescaled for gather)
  k_gemm<128,128,64,4,false,true><<<cdiv(n,32), 256, 0, stream>>>(
      x, W1, nullptr, nullptr, nullptr, dinv, nullptr, h1b, n);
  k_gather<128,true><<<GB, 256, 0, stream>>>(h1b, dinv, rowptr, eidx, b1, bufB, n);
  k_bn_stats<128><<<256, 256, 0, stream>>>(bufB, partials, n);
  k_bn_finalize<<<1, 128, 0, stream>>>(partials, stats, g1, be1, 128, 1.0f / n);
  k_bn_apply<128,true><<<cdiv((long long)n*32, BT), BT, 0, stream>>>(bufB, stats, h1pb, n);

  // ---- L2: SAGE 128->64, BN, LReLU ----
  k_gather<128,false><<<GB, 256, 0, stream>>>(h1pb, invcnt, rowptr, eidx, nullptr, bufC, n);
  k_gemm<128,64,32,2,true,false><<<cdiv(n,32), 256, 0, stream>>>(
      bufC, Wl2, bufB, Wr2, bl2, nullptr, bufD, nullptr, n);
  k_bn_stats<64><<<256, 256, 0, stream>>>(bufD, partials, n);
  k_bn_finalize<<<1, 64, 0, stream>>>(partials, stats, g2, be2, 64, 1.0f / n);
  k_bn_apply<64,false><<<cdiv((long long)n*16, BT), BT, 0, stream>>>(bufD, stats, nullptr, n);

  // ---- L3: GCN 64->32, BN, LReLU ----
  k_gemm<64,32,64,4,false,true><<<cdiv(n,128), 256, 0, stream>>>(
      bufD, W3, nullptr, nullptr, nullptr, dinv, nullptr, h3b, n);
  k_gather<32,true><<<GB, 256, 0, stream>>>(h3b, dinv, rowptr, eidx, b3, bufC, n);
  k_bn_stats<32><<<256, 256, 0, stream>>>(bufC, partials, n);
  k_bn_finalize<<<1, 32, 0, stream>>>(partials, stats, g3, be3, 32, 1.0f / n);
  k_bn_apply<32,false><<<cdiv((long long)n*8, BT), BT, 0, stream>>>(bufC, stats, nullptr, n);

  // ---- L4: GCN 32->32 (no BN) ----
  k_gemm<32,32,32,4,false,true><<<cdiv(n,128), 256, 0, stream>>>(
      bufC, W4, nullptr, nullptr, nullptr, dinv, nullptr, h4b, n);
  k_gather<32,true><<<GB, 256, 0, stream>>>(h4b, dinv, rowptr, eidx, b4, bufC, n);

  // ---- pool + link ----
  hipMemsetAsync(gpool, 0, (size_t)4096 * 32 * 4, stream);
  k_pool<<<cdiv((long long)n*8, BT), BT, 0, stream>>>(bufC, batch, gpool, n);
  k_link<<<cdiv(L, BT), BT, 0, stream>>>(gpool, li0, li1, (float*)d_out, L);
}

// Round 5
// 506.580 us; speedup vs baseline: 7.4374x; 1.0912x over previous
//
#include <hip/hip_runtime.h>
#include <math.h>

#define LEAK 0.01f
#define BNEPS 1e-5f
#define NCH 256   // chunks for hist/scatter phases

// ---------------- bf16 helpers ----------------
__device__ inline unsigned bfpack(float a, float b) {  // two f32 -> packed bf16 (RNE)
  unsigned ua = __float_as_uint(a);
  unsigned ub = __float_as_uint(b);
  unsigned ra = (ua + 0x7fffu + ((ua >> 16) & 1u)) >> 16;
  unsigned rb = (ub + 0x7fffu + ((ub >> 16) & 1u)) & 0xffff0000u;
  return ra | rb;
}
__device__ inline float2 bfunpack(unsigned u) {
  float2 r;
  r.x = __uint_as_float(u << 16);
  r.y = __uint_as_float(u & 0xffff0000u);
  return r;
}

// =======================================================================
// CSR build via bucketed counting sort (bucket = dst>>8, NBK<=256)
// =======================================================================
// phase 1: per-chunk bucket histograms -> H[bucket*NCH + chunk]
__global__ __launch_bounds__(256) void k_hist(const int* __restrict__ dst,
                                              int* __restrict__ H, int E, int NBK) {
  __shared__ int h[256];
  h[threadIdx.x] = 0;
  __syncthreads();
  int chunk = (E + NCH - 1) / NCH;
  int lo = blockIdx.x * chunk, hi = min(lo + chunk, E);
  for (int e = lo + threadIdx.x; e < hi; e += 256)
    atomicAdd(&h[dst[e] >> 8], 1);
  __syncthreads();
  if (threadIdx.x < NBK) H[threadIdx.x * NCH + blockIdx.x] = h[threadIdx.x];
}

// generic hierarchical exclusive scan (m elements, in -> out)
__global__ __launch_bounds__(256) void k_gscan1(const int* __restrict__ in,
                                                int* __restrict__ bsum, int m) {
  int i = blockIdx.x * 256 + threadIdx.x;
  int v = (i < m) ? in[i] : 0;
#pragma unroll
  for (int s = 1; s < 64; s <<= 1) v += __shfl_xor(v, s, 64);
  __shared__ int ws[4];
  if ((threadIdx.x & 63) == 0) ws[threadIdx.x >> 6] = v;
  __syncthreads();
  if (threadIdx.x == 0) bsum[blockIdx.x] = ws[0] + ws[1] + ws[2] + ws[3];
}
__global__ __launch_bounds__(256) void k_gscan2(int* __restrict__ bsum, int NB) {
  __shared__ int lds[256];
  int t = threadIdx.x;
  int v = (t < NB) ? bsum[t] : 0;
  lds[t] = v;
  __syncthreads();
  for (int ofs = 1; ofs < 256; ofs <<= 1) {
    int u = (t >= ofs) ? lds[t - ofs] : 0;
    __syncthreads();
    lds[t] += u;
    __syncthreads();
  }
  if (t < NB) bsum[t] = lds[t] - v;  // exclusive, in-place
}
__global__ __launch_bounds__(256) void k_gscan3(const int* __restrict__ in,
                                                const int* __restrict__ boff,
                                                int* __restrict__ out, int m) {
  __shared__ int lds[256];
  int t = threadIdx.x;
  int i = blockIdx.x * 256 + t;
  int v = (i < m) ? in[i] : 0;
  lds[t] = v;
  __syncthreads();
  for (int ofs = 1; ofs < 256; ofs <<= 1) {
    int u = (t >= ofs) ? lds[t - ofs] : 0;
    __syncthreads();
    lds[t] += u;
    __syncthreads();
  }
  if (i < m) out[i] = boff[blockIdx.x] + lds[t] - v;
}

// phase 3: scatter edges into per-(bucket,chunk) segments; pack src|dst_low<<24
__global__ __launch_bounds__(256) void k_scatter_bkt(
    const int* __restrict__ src, const int* __restrict__ dst,
    const int* __restrict__ O, int* __restrict__ ebuf, int E, int NBK) {
  __shared__ int cur[256];
  if (threadIdx.x < NBK) cur[threadIdx.x] = O[threadIdx.x * NCH + blockIdx.x];
  __syncthreads();
  int chunk = (E + NCH - 1) / NCH;
  int lo = blockIdx.x * chunk, hi = min(lo + chunk, E);
  for (int e = lo + threadIdx.x; e < hi; e += 256) {
    int d = dst[e];
    int pos = atomicAdd(&cur[d >> 8], 1);
    ebuf[pos] = src[e] | ((d & 255) << 24);   // requires n < 2^24
  }
}

// phase 4: one block per bucket: local hist+scan -> rowptr/deg/dinv/invcnt, fill eidx
__global__ __launch_bounds__(256) void k_fill2(
    const int* __restrict__ ebuf, const int* __restrict__ O,
    int* __restrict__ eidx, int* __restrict__ rowptr,
    float* __restrict__ dinv, float* __restrict__ invcnt,
    int E, int n, int NBK) {
  __shared__ int hist[256];
  __shared__ int sc[256];
  __shared__ int cur[256];
  const int b = blockIdx.x;
  const int t = threadIdx.x;
  const int lo = O[b * NCH];
  const int hi = (b + 1 < NBK) ? O[(b + 1) * NCH] : E;
  hist[t] = 0;
  __syncthreads();
  for (int e = lo + t; e < hi; e += 256)
    atomicAdd(&hist[(ebuf[e] >> 24) & 255], 1);
  __syncthreads();
  int v = hist[t];
  sc[t] = v;
  __syncthreads();
  for (int ofs = 1; ofs < 256; ofs <<= 1) {
    int u = (t >= ofs) ? sc[t - ofs] : 0;
    __syncthreads();
    sc[t] += u;
    __syncthreads();
  }
  int excl = sc[t] - v;
  cur[t] = lo + excl;
  int node = b * 256 + t;
  if (node < n) {
    rowptr[node] = lo + excl;
    float d = (float)v;
    dinv[node]   = rsqrtf(d + 1.0f);
    invcnt[node] = 1.0f / fmaxf(d, 1.0f);
  }
  if (node == n || (b == NBK - 1 && t == 255)) rowptr[n] = E;
  __syncthreads();
  for (int e = lo + t; e < hi; e += 256) {
    int p = ebuf[e];
    int pos = atomicAdd(&cur[(p >> 24) & 255], 1);
    eidx[pos] = p & 0xFFFFFF;
  }
}

// =======================================================================
// CSR gather aggregation over bf16 rows (one wave per node)
// GCN:  Hs holds dinv[r]*h[r]. out[v] = bias + dinv[v]*(sum_e Hs[s] + Hs[v])
// SAGE: Hs holds h[r].         out[v] = invcnt[v]*sum_e Hs[s]
// POOL: instead of storing, atomicAdd the row into gpool[batch[v]]
// =======================================================================
template<int F, bool GCN, bool OUTBF, bool POOL>
__global__ __launch_bounds__(256) void k_gather(
    const unsigned short* __restrict__ Hs, const float* __restrict__ scale,
    const int* __restrict__ rowptr, const int* __restrict__ eidx,
    const float* __restrict__ bias, float* __restrict__ outf,
    unsigned short* __restrict__ outb, const int* __restrict__ batch,
    float* __restrict__ gpool, int n) {
  constexpr int COLS = F / 8;       // lanes per edge (8 bf16 = 16 B each)
  constexpr int EPI  = 64 / COLS;   // edges per iteration
  const int v = blockIdx.x * 4 + (threadIdx.x >> 6);
  if (v >= n) return;
  const int lane = threadIdx.x & 63;
  const int col  = lane % COLS;
  const int eo   = lane / COLS;

  const int lo = rowptr[v], hi = rowptr[v + 1];
  float a[8] = {0.f,0.f,0.f,0.f,0.f,0.f,0.f,0.f};
  for (int i = lo + eo; i < hi; i += EPI) {
    int s = eidx[i];
    uint4 hv = *(const uint4*)&Hs[(long long)s * F + col * 8];
    float2 p0 = bfunpack(hv.x), p1 = bfunpack(hv.y);
    float2 p2 = bfunpack(hv.z), p3 = bfunpack(hv.w);
    a[0]+=p0.x; a[1]+=p0.y; a[2]+=p1.x; a[3]+=p1.y;
    a[4]+=p2.x; a[5]+=p2.y; a[6]+=p3.x; a[7]+=p3.y;
  }
#pragma unroll
  for (int m = COLS; m < 64; m <<= 1) {
#pragma unroll
    for (int j = 0; j < 8; j++) a[j] += __shfl_xor(a[j], m, 64);
  }
  if (eo == 0) {
    float sv = scale[v];
    float o[8];
    if constexpr (GCN) {
      uint4 hv = *(const uint4*)&Hs[(long long)v * F + col * 8];
      float2 p0 = bfunpack(hv.x), p1 = bfunpack(hv.y);
      float2 p2 = bfunpack(hv.z), p3 = bfunpack(hv.w);
      float h[8] = {p0.x,p0.y,p1.x,p1.y,p2.x,p2.y,p3.x,p3.y};
#pragma unroll
      for (int j = 0; j < 8; j++) o[j] = bias[col * 8 + j] + sv * (a[j] + h[j]);
    } else {
#pragma unroll
      for (int j = 0; j < 8; j++) o[j] = sv * a[j];
    }
    if constexpr (POOL) {
      int g = batch[v];
      float* dstp = &gpool[(long long)g * F + col * 8];
#pragma unroll
      for (int j = 0; j < 8; j++) atomicAdd(dstp + j, o[j]);
    } else if constexpr (OUTBF) {
      uint4 u;
      u.x = bfpack(o[0], o[1]); u.y = bfpack(o[2], o[3]);
      u.z = bfpack(o[4], o[5]); u.w = bfpack(o[6], o[7]);
      *(uint4*)&outb[(long long)v * F + col * 8] = u;
    } else {
      float4 o0 = {o[0],o[1],o[2],o[3]}, o1 = {o[4],o[5],o[6],o[7]};
      *(float4*)&outf[(long long)v * F + col * 8]     = o0;
      *(float4*)&outf[(long long)v * F + col * 8 + 4] = o1;
    }
  }
}

// ==== GEMM: Y = X1@Wa (+X2@Wb) (+bias); fp32/bf16 in, fp32/bf16(prescaled) out
template<int K, int FOUT, int KC, int R, bool DUAL, bool X1BF, bool X2BF, bool BF16OUT>
__global__ __launch_bounds__(256) void k_gemm(
    const void* __restrict__ X1v, const float* __restrict__ Wa,
    const void* __restrict__ X2v, const float* __restrict__ Wb,
    const float* __restrict__ bias, const float* __restrict__ prescale,
    float* __restrict__ Yf, unsigned short* __restrict__ Yb, int n) {
  constexpr int TPR  = FOUT / 4;
  constexpr int RGN  = 256 / TPR;
  constexpr int ROWS = RGN * R;
  __shared__ float sX1[ROWS * K];
  __shared__ float sX2[DUAL ? ROWS * K : 1];
  __shared__ float sWa[KC * FOUT];
  __shared__ float sWb[DUAL ? KC * FOUT : 1];

  const int row0 = blockIdx.x * ROWS;
  // stage X rows
  if constexpr (X1BF) {
    const unsigned short* X1 = (const unsigned short*)X1v;
    for (int i = threadIdx.x; i < ROWS * K / 8; i += 256) {
      int r = i / (K / 8), k8 = (i % (K / 8)) * 8;
      int gr = row0 + r;
      uint4 raw = {0,0,0,0};
      if (gr < n) raw = *(const uint4*)&X1[(long long)gr * K + k8];
      float2 p0 = bfunpack(raw.x), p1 = bfunpack(raw.y);
      float2 p2 = bfunpack(raw.z), p3 = bfunpack(raw.w);
      float4 lo = {p0.x,p0.y,p1.x,p1.y}, hi = {p2.x,p2.y,p3.x,p3.y};
      *(float4*)&sX1[r * K + k8]     = lo;
      *(float4*)&sX1[r * K + k8 + 4] = hi;
    }
  } else {
    const float* X1 = (const float*)X1v;
    for (int i = threadIdx.x; i < ROWS * K / 4; i += 256) {
      int r = i / (K / 4), k4 = (i % (K / 4)) * 4;
      int gr = row0 + r;
      float4 vv = {0,0,0,0};
      if (gr < n) vv = *(const float4*)&X1[(long long)gr * K + k4];
      *(float4*)&sX1[r * K + k4] = vv;
    }
  }
  if constexpr (DUAL) {
    if constexpr (X2BF) {
      const unsigned short* X2 = (const unsigned short*)X2v;
      for (int i = threadIdx.x; i < ROWS * K / 8; i += 256) {
        int r = i / (K / 8), k8 = (i % (K / 8)) * 8;
        int gr = row0 + r;
        uint4 raw = {0,0,0,0};
        if (gr < n) raw = *(const uint4*)&X2[(long long)gr * K + k8];
        float2 p0 = bfunpack(raw.x), p1 = bfunpack(raw.y);
        float2 p2 = bfunpack(raw.z), p3 = bfunpack(raw.w);
        float4 lo = {p0.x,p0.y,p1.x,p1.y}, hi = {p2.x,p2.y,p3.x,p3.y};
        *(float4*)&sX2[r * K + k8]     = lo;
        *(float4*)&sX2[r * K + k8 + 4] = hi;
      }
    } else {
      const float* X2 = (const float*)X2v;
      for (int i = threadIdx.x; i < ROWS * K / 4; i += 256) {
        int r = i / (K / 4), k4 = (i % (K / 4)) * 4;
        int gr = row0 + r;
        float4 vv = {0,0,0,0};
        if (gr < n) vv = *(const float4*)&X2[(long long)gr * K + k4];
        *(float4*)&sX2[r * K + k4] = vv;
      }
    }
  }

  const int cg = threadIdx.x % TPR;
  const int rg = threadIdx.x / TPR;
  const int jc = cg * 4;
  float4 acc[R];
#pragma unroll
  for (int i = 0; i < R; i++) acc[i] = {0.f,0.f,0.f,0.f};

  for (int k0 = 0; k0 < K; k0 += KC) {
    __syncthreads();
    for (int i = threadIdx.x; i < KC * FOUT / 4; i += 256) {
      int kk = i / (FOUT / 4), j4 = (i % (FOUT / 4)) * 4;
      *(float4*)&sWa[kk * FOUT + j4] = *(const float4*)&Wa[(long long)(k0 + kk) * FOUT + j4];
      if constexpr (DUAL)
        *(float4*)&sWb[kk * FOUT + j4] = *(const float4*)&Wb[(long long)(k0 + kk) * FOUT + j4];
    }
    __syncthreads();
#pragma unroll 8
    for (int kk = 0; kk < KC; kk++) {
      const float4 w = *(const float4*)&sWa[kk * FOUT + jc];
#pragma unroll
      for (int i = 0; i < R; i++) {
        float xv = sX1[(rg * R + i) * K + k0 + kk];
        acc[i].x = fmaf(xv, w.x, acc[i].x); acc[i].y = fmaf(xv, w.y, acc[i].y);
        acc[i].z = fmaf(xv, w.z, acc[i].z); acc[i].w = fmaf(xv, w.w, acc[i].w);
      }
      if constexpr (DUAL) {
        const float4 w2 = *(const float4*)&sWb[kk * FOUT + jc];
#pragma unroll
        for (int i = 0; i < R; i++) {
          float xv = sX2[(rg * R + i) * K + k0 + kk];
          acc[i].x = fmaf(xv, w2.x, acc[i].x); acc[i].y = fmaf(xv, w2.y, acc[i].y);
          acc[i].z = fmaf(xv, w2.z, acc[i].z); acc[i].w = fmaf(xv, w2.w, acc[i].w);
        }
      }
    }
  }
#pragma unroll
  for (int i = 0; i < R; i++) {
    int gr = row0 + rg * R + i;
    if (gr >= n) continue;
    float4 o = acc[i];
    if (bias) { o.x += bias[jc]; o.y += bias[jc+1]; o.z += bias[jc+2]; o.w += bias[jc+3]; }
    if constexpr (BF16OUT) {
      float ps = prescale ? prescale[gr] : 1.0f;
      uint2 u;
      u.x = bfpack(o.x * ps, o.y * ps);
      u.y = bfpack(o.z * ps, o.w * ps);
      *(uint2*)&Yb[(long long)gr * FOUT + jc] = u;
    } else {
      *(float4*)&Yf[(long long)gr * FOUT + jc] = o;
    }
  }
}

// ---------------- BatchNorm (training fwd, biased var) + LeakyReLU ----------
template<int F>
__global__ __launch_bounds__(256) void k_bn_stats(const float* __restrict__ Y,
                                                  float* __restrict__ partials, int n) {
  constexpr int RPB = 256 / F;
  int f  = threadIdx.x % F;
  int r0 = threadIdx.x / F;
  float s1 = 0.f, s2 = 0.f;
  for (long long r = (long long)blockIdx.x * RPB + r0; r < n; r += 256LL * RPB) {
    float v = Y[r * F + f];
    s1 += v; s2 += v * v;
  }
  __shared__ float ls1[256], ls2[256];
  ls1[threadIdx.x] = s1; ls2[threadIdx.x] = s2;
  __syncthreads();
  if (r0 == 0) {
#pragma unroll
    for (int i = 1; i < RPB; i++) { s1 += ls1[i * F + f]; s2 += ls2[i * F + f]; }
    partials[blockIdx.x * 2 * F + f]     = s1;
    partials[blockIdx.x * 2 * F + F + f] = s2;
  }
}

__global__ void k_bn_finalize(const float* __restrict__ partials, float* __restrict__ stats,
                              const float* __restrict__ g, const float* __restrict__ be,
                              int F, float invN) {
  int f = threadIdx.x;
  if (f >= F) return;
  float s1 = 0.f, s2 = 0.f;
  for (int b = 0; b < 256; b++) {
    s1 += partials[b * 2 * F + f];
    s2 += partials[b * 2 * F + F + f];
  }
  float m   = s1 * invN;
  float var = s2 * invN - m * m;
  float sc  = g[f] * rsqrtf(var + BNEPS);
  stats[f]     = sc;
  stats[F + f] = be[f] - m * sc;
}

// read fp32, write bf16 only
template<int F>
__global__ void k_bn_apply(const float* __restrict__ Y, const float* __restrict__ stats,
                           unsigned short* __restrict__ Yb, int n) {
  constexpr int TPR = F / 4;
  long long idx = (long long)blockIdx.x * blockDim.x + threadIdx.x;
  if (idx >= (long long)n * TPR) return;
  int fc = (int)(idx % TPR) * 4;
  const float4 sc = *(const float4*)&stats[fc];
  const float4 sh = *(const float4*)&stats[F + fc];
  float4 y = *(const float4*)&Y[idx * 4];
  y.x = fmaf(y.x, sc.x, sh.x); y.x = (y.x >= 0.f) ? y.x : LEAK * y.x;
  y.y = fmaf(y.y, sc.y, sh.y); y.y = (y.y >= 0.f) ? y.y : LEAK * y.y;
  y.z = fmaf(y.z, sc.z, sh.z); y.z = (y.z >= 0.f) ? y.z : LEAK * y.z;
  y.w = fmaf(y.w, sc.w, sh.w); y.w = (y.w >= 0.f) ? y.w : LEAK * y.w;
  uint2 u;
  u.x = bfpack(y.x, y.y);
  u.y = bfpack(y.z, y.w);
  *(uint2*)&Yb[idx * 4] = u;
}

// ---------------- link prediction ----------------
__global__ void k_link(const float* __restrict__ g, const int* __restrict__ li0,
                       const int* __restrict__ li1, float* __restrict__ out, int L) {
  int i = blockIdx.x * blockDim.x + threadIdx.x;
  if (i >= L) return;
  const float* a = g + (long long)li0[i] * 32;
  const float* b = g + (long long)li1[i] * 32;
  float s = 0.f;
#pragma unroll
  for (int f = 0; f < 32; f++) s = fmaf(a[f], b[f], s);
  out[i] = 1.0f / (1.0f + expf(-s));
}

// ---------------- launch ----------------
extern "C" void kernel_launch(void* const* d_in, const int* in_sizes, int n_in,
                              void* d_out, int out_size, void* d_ws, size_t ws_size,
                              hipStream_t stream) {
  const float* x   = (const float*)d_in[0];
  const int* ei    = (const int*)d_in[1];
  const int* batch = (const int*)d_in[2];
  const int* li    = (const int*)d_in[3];
  const float* W1  = (const float*)d_in[5];
  const float* b1  = (const float*)d_in[6];
  const float* g1  = (const float*)d_in[7];
  const float* be1 = (const float*)d_in[8];
  const float* Wl2 = (const float*)d_in[9];
  const float* bl2 = (const float*)d_in[10];
  const float* Wr2 = (const float*)d_in[11];
  const float* g2  = (const float*)d_in[12];
  const float* be2 = (const float*)d_in[13];
  const float* W3  = (const float*)d_in[14];
  const float* b3  = (const float*)d_in[15];
  const float* g3  = (const float*)d_in[16];
  const float* be3 = (const float*)d_in[17];
  const float* W4  = (const float*)d_in[18];
  const float* b4  = (const float*)d_in[19];

  const int n = in_sizes[0] / 128;   // 50000
  const int E = in_sizes[1] / 2;     // 800000
  const int L = in_sizes[3] / 2;     // 1000
  const int* src = ei;
  const int* dst = ei + E;
  const int* li0 = li;
  const int* li1 = li + L;
  const int NBK = (n + 255) / 256;   // dst buckets (<=256 for n<=65536)

  char* base = (char*)d_ws;
  size_t off = 0;
  auto alloc = [&](size_t bytes) -> void* {
    void* p = (void*)(base + off);
    off = (off + bytes + 255) & ~(size_t)255;
    return p;
  };
  int*   H      = (int*)alloc((size_t)NBK * NCH * 4);
  int*   O      = (int*)alloc((size_t)NBK * NCH * 4);
  int*   hsum   = (int*)alloc(1024 * 4);
  int*   ebuf   = (int*)alloc((size_t)E * 4);
  int*   eidx   = (int*)alloc((size_t)E * 4);
  int*   rowptr = (int*)alloc((size_t)(n + 1) * 4);
  float* dinv   = (float*)alloc((size_t)n * 4);
  float* invcnt = (float*)alloc((size_t)n * 4);
  float* stats  = (float*)alloc(512 * 4);
  float* partials = (float*)alloc((size_t)256 * 256 * 4);
  float* gpool  = (float*)alloc((size_t)1024 * 32 * 4);
  unsigned short* h1b  = (unsigned short*)alloc((size_t)n * 128 * 2); // dinv*(x@W1)
  unsigned short* h1pb = (unsigned short*)alloc((size_t)n * 128 * 2); // post-BN h1
  unsigned short* aggb = (unsigned short*)alloc((size_t)n * 128 * 2); // SAGE mean agg
  unsigned short* h2pb = (unsigned short*)alloc((size_t)n * 64 * 2);  // post-BN h2
  unsigned short* h3gb = (unsigned short*)alloc((size_t)n * 32 * 2);  // dinv*(h2'@W3)
  unsigned short* h3pb = (unsigned short*)alloc((size_t)n * 32 * 2);  // post-BN h3
  unsigned short* h4b  = (unsigned short*)alloc((size_t)n * 32 * 2);  // dinv*(h3'@W4)
  float* bufB   = (float*)alloc((size_t)n * 128 * 4);  // a1 (pre-BN fp32)
  float* bufD   = (float*)alloc((size_t)n * 64 * 4);   // h2 (pre-BN fp32)
  float* bufC   = (float*)alloc((size_t)n * 32 * 4);   // a3 (pre-BN fp32)
  (void)ws_size; (void)n_in; (void)out_size;

  const int BT = 256;
  auto cdiv = [](long long a, long long b) { return (int)((a + b - 1) / b); };
  const int GB  = cdiv(n, 4);                 // gather grid
  const int MH  = NBK * NCH;                  // histogram elements
  const int NBH = cdiv(MH, 256);              // scan blocks

  // ---- CSR build: bucketed counting sort ----
  k_hist<<<NCH, 256, 0, stream>>>(dst, H, E, NBK);
  k_gscan1<<<NBH, 256, 0, stream>>>(H, hsum, MH);
  k_gscan2<<<1, 256, 0, stream>>>(hsum, NBH);
  k_gscan3<<<NBH, 256, 0, stream>>>(H, hsum, O, MH);
  k_scatter_bkt<<<NCH, 256, 0, stream>>>(src, dst, O, ebuf, E, NBK);
  k_fill2<<<NBK, 256, 0, stream>>>(ebuf, O, eidx, rowptr, dinv, invcnt, E, n, NBK);

  // ---- L1: GCN 128->128, BN, LReLU ----
  k_gemm<128,128,64,4,false,false,false,true><<<cdiv(n,32), 256, 0, stream>>>(
      x, W1, nullptr, nullptr, nullptr, dinv, nullptr, h1b, n);
  k_gather<128,true,false,false><<<GB, 256, 0, stream>>>(
      h1b, dinv, rowptr, eidx, b1, bufB, nullptr, nullptr, nullptr, n);
  k_bn_stats<128><<<256, 256, 0, stream>>>(bufB, partials, n);
  k_bn_finalize<<<1, 128, 0, stream>>>(partials, stats, g1, be1, 128, 1.0f / n);
  k_bn_apply<128><<<cdiv((long long)n*32, BT), BT, 0, stream>>>(bufB, stats, h1pb, n);

  // ---- L2: SAGE 128->64, BN, LReLU ----
  k_gather<128,false,true,false><<<GB, 256, 0, stream>>>(
      h1pb, invcnt, rowptr, eidx, nullptr, nullptr, aggb, nullptr, nullptr, n);
  k_gemm<128,64,32,2,true,true,true,false><<<cdiv(n,32), 256, 0, stream>>>(
      aggb, Wl2, h1pb, Wr2, bl2, nullptr, bufD, nullptr, n);
  k_bn_stats<64><<<256, 256, 0, stream>>>(bufD, partials, n);
  k_bn_finalize<<<1, 64, 0, stream>>>(partials, stats, g2, be2, 64, 1.0f / n);
  k_bn_apply<64><<<cdiv((long long)n*16, BT), BT, 0, stream>>>(bufD, stats, h2pb, n);

  // ---- L3: GCN 64->32, BN, LReLU ----
  k_gemm<64,32,64,4,false,true,false,true><<<cdiv(n,128), 256, 0, stream>>>(
      h2pb, W3, nullptr, nullptr, nullptr, dinv, nullptr, h3gb, n);
  k_gather<32,true,false,false><<<GB, 256, 0, stream>>>(
      h3gb, dinv, rowptr, eidx, b3, bufC, nullptr, nullptr, nullptr, n);
  k_bn_stats<32><<<256, 256, 0, stream>>>(bufC, partials, n);
  k_bn_finalize<<<1, 32, 0, stream>>>(partials, stats, g3, be3, 32, 1.0f / n);
  k_bn_apply<32><<<cdiv((long long)n*8, BT), BT, 0, stream>>>(bufC, stats, h3pb, n);

  // ---- L4: GCN 32->32 + fused global-add-pool ----
  k_gemm<32,32,32,4,false,true,false,true><<<cdiv(n,128), 256, 0, stream>>>(
      h3pb, W4, nullptr, nullptr, nullptr, dinv, nullptr, h4b, n);
  hipMemsetAsync(gpool, 0, (size_t)1024 * 32 * 4, stream);
  k_gather<32,true,false,true><<<GB, 256, 0, stream>>>(
      h4b, dinv, rowptr, eidx, b4, nullptr, nullptr, batch, gpool, n);

  // ---- link ----
  k_link<<<cdiv(L, BT), BT, 0, stream>>>(gpool, li0, li1, (float*)d_out, L);
}

// Round 6
// 460.994 us; speedup vs baseline: 8.1729x; 1.0989x over previous
//
#include <hip/hip_runtime.h>
#include <math.h>

#define LEAK 0.01f
#define BNEPS 1e-5f
#define NCH 256   // chunks for hist/scatter phases

// ---------------- bf16 helpers ----------------
__device__ inline unsigned bfpack(float a, float b) {  // two f32 -> packed bf16 (RNE)
  unsigned ua = __float_as_uint(a);
  unsigned ub = __float_as_uint(b);
  unsigned ra = (ua + 0x7fffu + ((ua >> 16) & 1u)) >> 16;
  unsigned rb = (ub + 0x7fffu + ((ub >> 16) & 1u)) & 0xffff0000u;
  return ra | rb;
}
__device__ inline float2 bfunpack(unsigned u) {
  float2 r;
  r.x = __uint_as_float(u << 16);
  r.y = __uint_as_float(u & 0xffff0000u);
  return r;
}

// =======================================================================
// CSR build via bucketed counting sort (bucket = dst>>8, NBK<=256)
// =======================================================================
__global__ __launch_bounds__(256) void k_hist(const int* __restrict__ dst,
                                              int* __restrict__ H, int E, int NBK) {
  __shared__ int h[256];
  h[threadIdx.x] = 0;
  __syncthreads();
  int chunk = (E + NCH - 1) / NCH;
  int lo = blockIdx.x * chunk, hi = min(lo + chunk, E);
  for (int e = lo + threadIdx.x; e < hi; e += 256)
    atomicAdd(&h[dst[e] >> 8], 1);
  __syncthreads();
  if (threadIdx.x < NBK) H[threadIdx.x * NCH + blockIdx.x] = h[threadIdx.x];
}

__global__ __launch_bounds__(256) void k_gscan1(const int* __restrict__ in,
                                                int* __restrict__ bsum, int m) {
  int i = blockIdx.x * 256 + threadIdx.x;
  int v = (i < m) ? in[i] : 0;
#pragma unroll
  for (int s = 1; s < 64; s <<= 1) v += __shfl_xor(v, s, 64);
  __shared__ int ws[4];
  if ((threadIdx.x & 63) == 0) ws[threadIdx.x >> 6] = v;
  __syncthreads();
  if (threadIdx.x == 0) bsum[blockIdx.x] = ws[0] + ws[1] + ws[2] + ws[3];
}
__global__ __launch_bounds__(256) void k_gscan2(int* __restrict__ bsum, int NB) {
  __shared__ int lds[256];
  int t = threadIdx.x;
  int v = (t < NB) ? bsum[t] : 0;
  lds[t] = v;
  __syncthreads();
  for (int ofs = 1; ofs < 256; ofs <<= 1) {
    int u = (t >= ofs) ? lds[t - ofs] : 0;
    __syncthreads();
    lds[t] += u;
    __syncthreads();
  }
  if (t < NB) bsum[t] = lds[t] - v;  // exclusive, in-place
}
__global__ __launch_bounds__(256) void k_gscan3(const int* __restrict__ in,
                                                const int* __restrict__ boff,
                                                int* __restrict__ out, int m) {
  __shared__ int lds[256];
  int t = threadIdx.x;
  int i = blockIdx.x * 256 + t;
  int v = (i < m) ? in[i] : 0;
  lds[t] = v;
  __syncthreads();
  for (int ofs = 1; ofs < 256; ofs <<= 1) {
    int u = (t >= ofs) ? lds[t - ofs] : 0;
    __syncthreads();
    lds[t] += u;
    __syncthreads();
  }
  if (i < m) out[i] = boff[blockIdx.x] + lds[t] - v;
}

__global__ __launch_bounds__(256) void k_scatter_bkt(
    const int* __restrict__ src, const int* __restrict__ dst,
    const int* __restrict__ O, int* __restrict__ ebuf, int E, int NBK) {
  __shared__ int cur[256];
  if (threadIdx.x < NBK) cur[threadIdx.x] = O[threadIdx.x * NCH + blockIdx.x];
  __syncthreads();
  int chunk = (E + NCH - 1) / NCH;
  int lo = blockIdx.x * chunk, hi = min(lo + chunk, E);
  for (int e = lo + threadIdx.x; e < hi; e += 256) {
    int d = dst[e];
    int pos = atomicAdd(&cur[d >> 8], 1);
    ebuf[pos] = src[e] | ((d & 255) << 24);   // requires n < 2^24
  }
}

__global__ __launch_bounds__(256) void k_fill2(
    const int* __restrict__ ebuf, const int* __restrict__ O,
    int* __restrict__ eidx, int* __restrict__ rowptr,
    float* __restrict__ dinv, float* __restrict__ invcnt,
    int E, int n, int NBK) {
  __shared__ int hist[256];
  __shared__ int sc[256];
  __shared__ int cur[256];
  const int b = blockIdx.x;
  const int t = threadIdx.x;
  const int lo = O[b * NCH];
  const int hi = (b + 1 < NBK) ? O[(b + 1) * NCH] : E;
  hist[t] = 0;
  __syncthreads();
  for (int e = lo + t; e < hi; e += 256)
    atomicAdd(&hist[(ebuf[e] >> 24) & 255], 1);
  __syncthreads();
  int v = hist[t];
  sc[t] = v;
  __syncthreads();
  for (int ofs = 1; ofs < 256; ofs <<= 1) {
    int u = (t >= ofs) ? sc[t - ofs] : 0;
    __syncthreads();
    sc[t] += u;
    __syncthreads();
  }
  int excl = sc[t] - v;
  cur[t] = lo + excl;
  int node = b * 256 + t;
  if (node < n) {
    rowptr[node] = lo + excl;
    float d = (float)v;
    dinv[node]   = rsqrtf(d + 1.0f);
    invcnt[node] = 1.0f / fmaxf(d, 1.0f);
  }
  if (node == n || (b == NBK - 1 && t == 255)) rowptr[n] = E;
  __syncthreads();
  for (int e = lo + t; e < hi; e += 256) {
    int p = ebuf[e];
    int pos = atomicAdd(&cur[(p >> 24) & 255], 1);
    eidx[pos] = p & 0xFFFFFF;
  }
}

// =======================================================================
// CSR gather aggregation over bf16 rows (one wave per node)
// GCN:  Hs = dinv[r]*h[r]. o = bias + dinv[v]*(sum_e Hs[s] + Hs[v])
// ADD:  o = scale[v]*sum_e Hs[s] + addf[v]   (SAGE: scale=invcnt, addf=x@Wr+bl)
// else: o = scale[v]*sum_e Hs[s]
// POOL: atomicAdd row into gpool[batch[v]], else write bf16 (OUTBF) or fp32
// =======================================================================
template<int F, bool GCN, bool OUTBF, bool POOL, bool ADD>
__global__ __launch_bounds__(256) void k_gather(
    const unsigned short* __restrict__ Hs, const float* __restrict__ scale,
    const int* __restrict__ rowptr, const int* __restrict__ eidx,
    const float* __restrict__ bias, const float* __restrict__ addf,
    float* __restrict__ outf, unsigned short* __restrict__ outb,
    const int* __restrict__ batch, float* __restrict__ gpool, int n) {
  constexpr int COLS = F / 8;       // lanes per edge (8 bf16 = 16 B each)
  constexpr int EPI  = 64 / COLS;   // edges per iteration
  const int v = blockIdx.x * 4 + (threadIdx.x >> 6);
  if (v >= n) return;
  const int lane = threadIdx.x & 63;
  const int col  = lane % COLS;
  const int eo   = lane / COLS;

  const int lo = rowptr[v], hi = rowptr[v + 1];
  float a[8] = {0.f,0.f,0.f,0.f,0.f,0.f,0.f,0.f};
  for (int i = lo + eo; i < hi; i += EPI) {
    int s = eidx[i];
    uint4 hv = *(const uint4*)&Hs[(long long)s * F + col * 8];
    float2 p0 = bfunpack(hv.x), p1 = bfunpack(hv.y);
    float2 p2 = bfunpack(hv.z), p3 = bfunpack(hv.w);
    a[0]+=p0.x; a[1]+=p0.y; a[2]+=p1.x; a[3]+=p1.y;
    a[4]+=p2.x; a[5]+=p2.y; a[6]+=p3.x; a[7]+=p3.y;
  }
#pragma unroll
  for (int m = COLS; m < 64; m <<= 1) {
#pragma unroll
    for (int j = 0; j < 8; j++) a[j] += __shfl_xor(a[j], m, 64);
  }
  if (eo == 0) {
    float sv = scale[v];
    float o[8];
    if constexpr (GCN) {
      uint4 hv = *(const uint4*)&Hs[(long long)v * F + col * 8];
      float2 p0 = bfunpack(hv.x), p1 = bfunpack(hv.y);
      float2 p2 = bfunpack(hv.z), p3 = bfunpack(hv.w);
      float h[8] = {p0.x,p0.y,p1.x,p1.y,p2.x,p2.y,p3.x,p3.y};
#pragma unroll
      for (int j = 0; j < 8; j++) o[j] = bias[col * 8 + j] + sv * (a[j] + h[j]);
    } else if constexpr (ADD) {
      const float4 t0 = *(const float4*)&addf[(long long)v * F + col * 8];
      const float4 t1 = *(const float4*)&addf[(long long)v * F + col * 8 + 4];
      o[0]=fmaf(sv,a[0],t0.x); o[1]=fmaf(sv,a[1],t0.y);
      o[2]=fmaf(sv,a[2],t0.z); o[3]=fmaf(sv,a[3],t0.w);
      o[4]=fmaf(sv,a[4],t1.x); o[5]=fmaf(sv,a[5],t1.y);
      o[6]=fmaf(sv,a[6],t1.z); o[7]=fmaf(sv,a[7],t1.w);
    } else {
#pragma unroll
      for (int j = 0; j < 8; j++) o[j] = sv * a[j];
    }
    if constexpr (POOL) {
      int g = batch[v];
      float* dstp = &gpool[(long long)g * F + col * 8];
#pragma unroll
      for (int j = 0; j < 8; j++) atomicAdd(dstp + j, o[j]);
    } else if constexpr (OUTBF) {
      uint4 u;
      u.x = bfpack(o[0], o[1]); u.y = bfpack(o[2], o[3]);
      u.z = bfpack(o[4], o[5]); u.w = bfpack(o[6], o[7]);
      *(uint4*)&outb[(long long)v * F + col * 8] = u;
    } else {
      float4 o0 = {o[0],o[1],o[2],o[3]}, o1 = {o[4],o[5],o[6],o[7]};
      *(float4*)&outf[(long long)v * F + col * 8]     = o0;
      *(float4*)&outf[(long long)v * F + col * 8 + 4] = o1;
    }
  }
}

// ==== GEMM: Y = X1@Wa (+bias); fp32/bf16 in, bf16(prescaled) out ====
template<int K, int FOUT, int KC, int R, bool X1BF>
__global__ __launch_bounds__(256) void k_gemm(
    const void* __restrict__ X1v, const float* __restrict__ Wa,
    const float* __restrict__ bias, const float* __restrict__ prescale,
    unsigned short* __restrict__ Yb, int n) {
  constexpr int TPR  = FOUT / 4;
  constexpr int RGN  = 256 / TPR;
  constexpr int ROWS = RGN * R;
  __shared__ float sX1[ROWS * K];
  __shared__ float sWa[KC * FOUT];

  const int row0 = blockIdx.x * ROWS;
  if constexpr (X1BF) {
    const unsigned short* X1 = (const unsigned short*)X1v;
    for (int i = threadIdx.x; i < ROWS * K / 8; i += 256) {
      int r = i / (K / 8), k8 = (i % (K / 8)) * 8;
      int gr = row0 + r;
      uint4 raw = {0,0,0,0};
      if (gr < n) raw = *(const uint4*)&X1[(long long)gr * K + k8];
      float2 p0 = bfunpack(raw.x), p1 = bfunpack(raw.y);
      float2 p2 = bfunpack(raw.z), p3 = bfunpack(raw.w);
      float4 lo = {p0.x,p0.y,p1.x,p1.y}, hi = {p2.x,p2.y,p3.x,p3.y};
      *(float4*)&sX1[r * K + k8]     = lo;
      *(float4*)&sX1[r * K + k8 + 4] = hi;
    }
  } else {
    const float* X1 = (const float*)X1v;
    for (int i = threadIdx.x; i < ROWS * K / 4; i += 256) {
      int r = i / (K / 4), k4 = (i % (K / 4)) * 4;
      int gr = row0 + r;
      float4 vv = {0,0,0,0};
      if (gr < n) vv = *(const float4*)&X1[(long long)gr * K + k4];
      *(float4*)&sX1[r * K + k4] = vv;
    }
  }

  const int cg = threadIdx.x % TPR;
  const int rg = threadIdx.x / TPR;
  const int jc = cg * 4;
  float4 acc[R];
#pragma unroll
  for (int i = 0; i < R; i++) acc[i] = {0.f,0.f,0.f,0.f};

  for (int k0 = 0; k0 < K; k0 += KC) {
    __syncthreads();
    for (int i = threadIdx.x; i < KC * FOUT / 4; i += 256) {
      int kk = i / (FOUT / 4), j4 = (i % (FOUT / 4)) * 4;
      *(float4*)&sWa[kk * FOUT + j4] = *(const float4*)&Wa[(long long)(k0 + kk) * FOUT + j4];
    }
    __syncthreads();
#pragma unroll 8
    for (int kk = 0; kk < KC; kk++) {
      const float4 w = *(const float4*)&sWa[kk * FOUT + jc];
#pragma unroll
      for (int i = 0; i < R; i++) {
        float xv = sX1[(rg * R + i) * K + k0 + kk];
        acc[i].x = fmaf(xv, w.x, acc[i].x); acc[i].y = fmaf(xv, w.y, acc[i].y);
        acc[i].z = fmaf(xv, w.z, acc[i].z); acc[i].w = fmaf(xv, w.w, acc[i].w);
      }
    }
  }
#pragma unroll
  for (int i = 0; i < R; i++) {
    int gr = row0 + rg * R + i;
    if (gr >= n) continue;
    float4 o = acc[i];
    if (bias) { o.x += bias[jc]; o.y += bias[jc+1]; o.z += bias[jc+2]; o.w += bias[jc+3]; }
    float ps = prescale ? prescale[gr] : 1.0f;
    uint2 u;
    u.x = bfpack(o.x * ps, o.y * ps);
    u.y = bfpack(o.z * ps, o.w * ps);
    *(uint2*)&Yb[(long long)gr * FOUT + jc] = u;
  }
}

// ==== SAGE dual GEMM: t1 = X@Wl (bf16), t2 = X@Wr + bl (fp32); K=128, F=64 ==
template<int R>
__global__ __launch_bounds__(256) void k_gemm_sage(
    const unsigned short* __restrict__ X, const float* __restrict__ Wl,
    const float* __restrict__ Wr, const float* __restrict__ bl,
    unsigned short* __restrict__ t1, float* __restrict__ t2, int n) {
  constexpr int K = 128, F = 64, KC = 64;
  constexpr int TPR = F / 4;          // 16
  constexpr int RGN = 256 / TPR;      // 16
  constexpr int ROWS = RGN * R;       // 32 for R=2
  __shared__ float sX[ROWS * K];
  __shared__ float sWl[KC * F];
  __shared__ float sWr[KC * F];

  const int row0 = blockIdx.x * ROWS;
  for (int i = threadIdx.x; i < ROWS * K / 8; i += 256) {
    int r = i / (K / 8), k8 = (i % (K / 8)) * 8;
    int gr = row0 + r;
    uint4 raw = {0,0,0,0};
    if (gr < n) raw = *(const uint4*)&X[(long long)gr * K + k8];
    float2 p0 = bfunpack(raw.x), p1 = bfunpack(raw.y);
    float2 p2 = bfunpack(raw.z), p3 = bfunpack(raw.w);
    float4 lo = {p0.x,p0.y,p1.x,p1.y}, hi = {p2.x,p2.y,p3.x,p3.y};
    *(float4*)&sX[r * K + k8]     = lo;
    *(float4*)&sX[r * K + k8 + 4] = hi;
  }

  const int cg = threadIdx.x % TPR;
  const int rg = threadIdx.x / TPR;
  const int jc = cg * 4;
  float4 a1[R], a2[R];
#pragma unroll
  for (int i = 0; i < R; i++) { a1[i] = {0,0,0,0}; a2[i] = {0,0,0,0}; }

  for (int k0 = 0; k0 < K; k0 += KC) {
    __syncthreads();
    for (int i = threadIdx.x; i < KC * F / 4; i += 256) {
      int kk = i / (F / 4), j4 = (i % (F / 4)) * 4;
      *(float4*)&sWl[kk * F + j4] = *(const float4*)&Wl[(long long)(k0 + kk) * F + j4];
      *(float4*)&sWr[kk * F + j4] = *(const float4*)&Wr[(long long)(k0 + kk) * F + j4];
    }
    __syncthreads();
#pragma unroll 8
    for (int kk = 0; kk < KC; kk++) {
      const float4 wl = *(const float4*)&sWl[kk * F + jc];
      const float4 wr = *(const float4*)&sWr[kk * F + jc];
#pragma unroll
      for (int i = 0; i < R; i++) {
        float xv = sX[(rg * R + i) * K + k0 + kk];
        a1[i].x = fmaf(xv, wl.x, a1[i].x); a1[i].y = fmaf(xv, wl.y, a1[i].y);
        a1[i].z = fmaf(xv, wl.z, a1[i].z); a1[i].w = fmaf(xv, wl.w, a1[i].w);
        a2[i].x = fmaf(xv, wr.x, a2[i].x); a2[i].y = fmaf(xv, wr.y, a2[i].y);
        a2[i].z = fmaf(xv, wr.z, a2[i].z); a2[i].w = fmaf(xv, wr.w, a2[i].w);
      }
    }
  }
#pragma unroll
  for (int i = 0; i < R; i++) {
    int gr = row0 + rg * R + i;
    if (gr >= n) continue;
    uint2 u;
    u.x = bfpack(a1[i].x, a1[i].y);
    u.y = bfpack(a1[i].z, a1[i].w);
    *(uint2*)&t1[(long long)gr * F + jc] = u;
    float4 o = a2[i];
    o.x += bl[jc]; o.y += bl[jc+1]; o.z += bl[jc+2]; o.w += bl[jc+3];
    *(float4*)&t2[(long long)gr * F + jc] = o;
  }
}

// ---------------- BatchNorm (training fwd, biased var) + LeakyReLU ----------
// stats from bf16 input (consistent with what bn_apply reads)
template<int F>
__global__ __launch_bounds__(256) void k_bn_stats(const unsigned short* __restrict__ Y,
                                                  float* __restrict__ partials, int n) {
  constexpr int FP  = F / 2;          // uint (2 bf16) per row handled per thread
  constexpr int RPB = 256 / FP;
  const int f2 = threadIdx.x % FP;
  const int r0 = threadIdx.x / FP;
  const unsigned* Yu = (const unsigned*)Y;
  float s1a = 0.f, s2a = 0.f, s1b = 0.f, s2b = 0.f;
  for (long long r = (long long)blockIdx.x * RPB + r0; r < n; r += 256LL * RPB) {
    float2 p = bfunpack(Yu[r * FP + f2]);
    s1a += p.x; s2a += p.x * p.x;
    s1b += p.y; s2b += p.y * p.y;
  }
  __shared__ float l1a[256], l2a[256], l1b[256], l2b[256];
  l1a[threadIdx.x] = s1a; l2a[threadIdx.x] = s2a;
  l1b[threadIdx.x] = s1b; l2b[threadIdx.x] = s2b;
  __syncthreads();
  if (r0 == 0) {
#pragma unroll
    for (int i = 1; i < RPB; i++) {
      s1a += l1a[i * FP + f2]; s2a += l2a[i * FP + f2];
      s1b += l1b[i * FP + f2]; s2b += l2b[i * FP + f2];
    }
    float* p = &partials[blockIdx.x * 2 * F];
    p[2 * f2]         = s1a;
    p[2 * f2 + 1]     = s1b;
    p[F + 2 * f2]     = s2a;
    p[F + 2 * f2 + 1] = s2b;
  }
}

__global__ void k_bn_finalize(const float* __restrict__ partials, float* __restrict__ stats,
                              const float* __restrict__ g, const float* __restrict__ be,
                              int F, float invN) {
  int f = threadIdx.x;
  if (f >= F) return;
  float s1 = 0.f, s2 = 0.f;
  for (int b = 0; b < 256; b++) {
    s1 += partials[b * 2 * F + f];
    s2 += partials[b * 2 * F + F + f];
  }
  float m   = s1 * invN;
  float var = s2 * invN - m * m;
  float sc  = g[f] * rsqrtf(var + BNEPS);
  stats[f]     = sc;
  stats[F + f] = be[f] - m * sc;
}

// bf16 in -> BN+lrelu -> bf16 out
template<int F>
__global__ void k_bn_apply(const unsigned short* __restrict__ Yin,
                           const float* __restrict__ stats,
                           unsigned short* __restrict__ Yout, int n) {
  constexpr int TPR = F / 4;
  long long idx = (long long)blockIdx.x * blockDim.x + threadIdx.x;
  if (idx >= (long long)n * TPR) return;
  int fc = (int)(idx % TPR) * 4;
  const float4 sc = *(const float4*)&stats[fc];
  const float4 sh = *(const float4*)&stats[F + fc];
  uint2 raw = *(const uint2*)&Yin[idx * 4];
  float2 p0 = bfunpack(raw.x), p1 = bfunpack(raw.y);
  float4 y = {p0.x, p0.y, p1.x, p1.y};
  y.x = fmaf(y.x, sc.x, sh.x); y.x = (y.x >= 0.f) ? y.x : LEAK * y.x;
  y.y = fmaf(y.y, sc.y, sh.y); y.y = (y.y >= 0.f) ? y.y : LEAK * y.y;
  y.z = fmaf(y.z, sc.z, sh.z); y.z = (y.z >= 0.f) ? y.z : LEAK * y.z;
  y.w = fmaf(y.w, sc.w, sh.w); y.w = (y.w >= 0.f) ? y.w : LEAK * y.w;
  uint2 u;
  u.x = bfpack(y.x, y.y);
  u.y = bfpack(y.z, y.w);
  *(uint2*)&Yout[idx * 4] = u;
}

// ---------------- link prediction ----------------
__global__ void k_link(const float* __restrict__ g, const int* __restrict__ li0,
                       const int* __restrict__ li1, float* __restrict__ out, int L) {
  int i = blockIdx.x * blockDim.x + threadIdx.x;
  if (i >= L) return;
  const float* a = g + (long long)li0[i] * 32;
  const float* b = g + (long long)li1[i] * 32;
  float s = 0.f;
#pragma unroll
  for (int f = 0; f < 32; f++) s = fmaf(a[f], b[f], s);
  out[i] = 1.0f / (1.0f + expf(-s));
}

// ---------------- launch ----------------
extern "C" void kernel_launch(void* const* d_in, const int* in_sizes, int n_in,
                              void* d_out, int out_size, void* d_ws, size_t ws_size,
                              hipStream_t stream) {
  const float* x   = (const float*)d_in[0];
  const int* ei    = (const int*)d_in[1];
  const int* batch = (const int*)d_in[2];
  const int* li    = (const int*)d_in[3];
  const float* W1  = (const float*)d_in[5];
  const float* b1  = (const float*)d_in[6];
  const float* g1  = (const float*)d_in[7];
  const float* be1 = (const float*)d_in[8];
  const float* Wl2 = (const float*)d_in[9];
  const float* bl2 = (const float*)d_in[10];
  const float* Wr2 = (const float*)d_in[11];
  const float* g2  = (const float*)d_in[12];
  const float* be2 = (const float*)d_in[13];
  const float* W3  = (const float*)d_in[14];
  const float* b3  = (const float*)d_in[15];
  const float* g3  = (const float*)d_in[16];
  const float* be3 = (const float*)d_in[17];
  const float* W4  = (const float*)d_in[18];
  const float* b4  = (const float*)d_in[19];

  const int n = in_sizes[0] / 128;   // 50000
  const int E = in_sizes[1] / 2;     // 800000
  const int L = in_sizes[3] / 2;     // 1000
  const int* src = ei;
  const int* dst = ei + E;
  const int* li0 = li;
  const int* li1 = li + L;
  const int NBK = (n + 255) / 256;   // dst buckets (<=256 for n<=65536)

  char* base = (char*)d_ws;
  size_t off = 0;
  auto alloc = [&](size_t bytes) -> void* {
    void* p = (void*)(base + off);
    off = (off + bytes + 255) & ~(size_t)255;
    return p;
  };
  int*   H      = (int*)alloc((size_t)NBK * NCH * 4);
  int*   O      = (int*)alloc((size_t)NBK * NCH * 4);
  int*   hsum   = (int*)alloc(1024 * 4);
  int*   ebuf   = (int*)alloc((size_t)E * 4);
  int*   eidx   = (int*)alloc((size_t)E * 4);
  int*   rowptr = (int*)alloc((size_t)(n + 1) * 4);
  float* dinv   = (float*)alloc((size_t)n * 4);
  float* invcnt = (float*)alloc((size_t)n * 4);
  float* stats  = (float*)alloc(512 * 4);
  float* partials = (float*)alloc((size_t)256 * 256 * 4);
  float* gpool  = (float*)alloc((size_t)1024 * 32 * 4);
  unsigned short* h1b  = (unsigned short*)alloc((size_t)n * 128 * 2); // dinv*(x@W1)
  unsigned short* a1b  = (unsigned short*)alloc((size_t)n * 128 * 2); // pre-BN a1
  unsigned short* h1pb = (unsigned short*)alloc((size_t)n * 128 * 2); // post-BN h1
  unsigned short* t1b  = (unsigned short*)alloc((size_t)n * 64 * 2);  // h1'@Wl2
  float*          t2f  = (float*)alloc((size_t)n * 64 * 4);           // h1'@Wr2+bl2
  unsigned short* h2b  = (unsigned short*)alloc((size_t)n * 64 * 2);  // pre-BN h2
  unsigned short* h2pb = (unsigned short*)alloc((size_t)n * 64 * 2);  // post-BN h2
  unsigned short* h3gb = (unsigned short*)alloc((size_t)n * 32 * 2);  // dinv*(h2'@W3)
  unsigned short* a3b  = (unsigned short*)alloc((size_t)n * 32 * 2);  // pre-BN a3
  unsigned short* h3pb = (unsigned short*)alloc((size_t)n * 32 * 2);  // post-BN h3
  unsigned short* h4b  = (unsigned short*)alloc((size_t)n * 32 * 2);  // dinv*(h3'@W4)
  (void)ws_size; (void)n_in; (void)out_size;

  const int BT = 256;
  auto cdiv = [](long long a, long long b) { return (int)((a + b - 1) / b); };
  const int GB  = cdiv(n, 4);                 // gather grid
  const int MH  = NBK * NCH;                  // histogram elements
  const int NBH = cdiv(MH, 256);              // scan blocks

  // ---- CSR build: bucketed counting sort ----
  k_hist<<<NCH, 256, 0, stream>>>(dst, H, E, NBK);
  k_gscan1<<<NBH, 256, 0, stream>>>(H, hsum, MH);
  k_gscan2<<<1, 256, 0, stream>>>(hsum, NBH);
  k_gscan3<<<NBH, 256, 0, stream>>>(H, hsum, O, MH);
  k_scatter_bkt<<<NCH, 256, 0, stream>>>(src, dst, O, ebuf, E, NBK);
  k_fill2<<<NBK, 256, 0, stream>>>(ebuf, O, eidx, rowptr, dinv, invcnt, E, n, NBK);

  // ---- L1: GCN 128->128, BN, LReLU ----
  k_gemm<128,128,64,4,false><<<cdiv(n,32), 256, 0, stream>>>(
      x, W1, nullptr, dinv, h1b, n);
  k_gather<128,true,true,false,false><<<GB, 256, 0, stream>>>(
      h1b, dinv, rowptr, eidx, b1, nullptr, nullptr, a1b, nullptr, nullptr, n);
  k_bn_stats<128><<<256, 256, 0, stream>>>(a1b, partials, n);
  k_bn_finalize<<<1, 128, 0, stream>>>(partials, stats, g1, be1, 128, 1.0f / n);
  k_bn_apply<128><<<cdiv((long long)n*32, BT), BT, 0, stream>>>(a1b, stats, h1pb, n);

  // ---- L2: SAGE 128->64 (transform-before-aggregate), BN, LReLU ----
  k_gemm_sage<2><<<cdiv(n,32), 256, 0, stream>>>(h1pb, Wl2, Wr2, bl2, t1b, t2f, n);
  k_gather<64,false,true,false,true><<<GB, 256, 0, stream>>>(
      t1b, invcnt, rowptr, eidx, nullptr, t2f, nullptr, h2b, nullptr, nullptr, n);
  k_bn_stats<64><<<256, 256, 0, stream>>>(h2b, partials, n);
  k_bn_finalize<<<1, 64, 0, stream>>>(partials, stats, g2, be2, 64, 1.0f / n);
  k_bn_apply<64><<<cdiv((long long)n*16, BT), BT, 0, stream>>>(h2b, stats, h2pb, n);

  // ---- L3: GCN 64->32, BN, LReLU ----
  k_gemm<64,32,64,4,true><<<cdiv(n,128), 256, 0, stream>>>(
      h2pb, W3, nullptr, dinv, h3gb, n);
  k_gather<32,true,true,false,false><<<GB, 256, 0, stream>>>(
      h3gb, dinv, rowptr, eidx, b3, nullptr, nullptr, a3b, nullptr, nullptr, n);
  k_bn_stats<32><<<256, 256, 0, stream>>>(a3b, partials, n);
  k_bn_finalize<<<1, 32, 0, stream>>>(partials, stats, g3, be3, 32, 1.0f / n);
  k_bn_apply<32><<<cdiv((long long)n*8, BT), BT, 0, stream>>>(a3b, stats, h3pb, n);

  // ---- L4: GCN 32->32 + fused global-add-pool ----
  k_gemm<32,32,32,4,true><<<cdiv(n,128), 256, 0, stream>>>(
      h3pb, W4, nullptr, dinv, h4b, n);
  hipMemsetAsync(gpool, 0, (size_t)1024 * 32 * 4, stream);
  k_gather<32,true,false,true,false><<<GB, 256, 0, stream>>>(
      h4b, dinv, rowptr, eidx, b4, nullptr, nullptr, nullptr, batch, gpool, n);

  // ---- link ----
  k_link<<<cdiv(L, BT), BT, 0, stream>>>(gpool, li0, li1, (float*)d_out, L);
}

// Round 7
// 410.576 us; speedup vs baseline: 9.1765x; 1.1228x over previous
//
#include <hip/hip_runtime.h>
#include <math.h>

#define LEAK 0.01f
#define BNEPS 1e-5f
#define NCH 256   // chunks for hist/scatter phases
#define NGMAX 1024

// ---------------- bf16 helpers ----------------
__device__ inline unsigned bfpack(float a, float b) {  // two f32 -> packed bf16 (RNE)
  unsigned ua = __float_as_uint(a);
  unsigned ub = __float_as_uint(b);
  unsigned ra = (ua + 0x7fffu + ((ua >> 16) & 1u)) >> 16;
  unsigned rb = (ub + 0x7fffu + ((ub >> 16) & 1u)) & 0xffff0000u;
  return ra | rb;
}
__device__ inline float2 bfunpack(unsigned u) {
  float2 r;
  r.x = __uint_as_float(u << 16);
  r.y = __uint_as_float(u & 0xffff0000u);
  return r;
}

// =======================================================================
// CSR build via bucketed counting sort (bucket = dst>>8, NBK<=256)
// =======================================================================
__global__ __launch_bounds__(256) void k_hist(const int* __restrict__ dst,
                                              int* __restrict__ H, int E, int NBK) {
  __shared__ int h[256];
  h[threadIdx.x] = 0;
  __syncthreads();
  int chunk = (E + NCH - 1) / NCH;
  int lo = blockIdx.x * chunk, hi = min(lo + chunk, E);
  for (int e = lo + threadIdx.x; e < hi; e += 256)
    atomicAdd(&h[dst[e] >> 8], 1);
  __syncthreads();
  if (threadIdx.x < NBK) H[threadIdx.x * NCH + blockIdx.x] = h[threadIdx.x];
}

__global__ __launch_bounds__(256) void k_gscan1(const int* __restrict__ in,
                                                int* __restrict__ bsum, int m) {
  int i = blockIdx.x * 256 + threadIdx.x;
  int v = (i < m) ? in[i] : 0;
#pragma unroll
  for (int s = 1; s < 64; s <<= 1) v += __shfl_xor(v, s, 64);
  __shared__ int ws[4];
  if ((threadIdx.x & 63) == 0) ws[threadIdx.x >> 6] = v;
  __syncthreads();
  if (threadIdx.x == 0) bsum[blockIdx.x] = ws[0] + ws[1] + ws[2] + ws[3];
}
__global__ __launch_bounds__(256) void k_gscan2(int* __restrict__ bsum, int NB) {
  __shared__ int lds[256];
  int t = threadIdx.x;
  int v = (t < NB) ? bsum[t] : 0;
  lds[t] = v;
  __syncthreads();
  for (int ofs = 1; ofs < 256; ofs <<= 1) {
    int u = (t >= ofs) ? lds[t - ofs] : 0;
    __syncthreads();
    lds[t] += u;
    __syncthreads();
  }
  if (t < NB) bsum[t] = lds[t] - v;  // exclusive, in-place
}
__global__ __launch_bounds__(256) void k_gscan3(const int* __restrict__ in,
                                                const int* __restrict__ boff,
                                                int* __restrict__ out, int m) {
  __shared__ int lds[256];
  int t = threadIdx.x;
  int i = blockIdx.x * 256 + t;
  int v = (i < m) ? in[i] : 0;
  lds[t] = v;
  __syncthreads();
  for (int ofs = 1; ofs < 256; ofs <<= 1) {
    int u = (t >= ofs) ? lds[t - ofs] : 0;
    __syncthreads();
    lds[t] += u;
    __syncthreads();
  }
  if (i < m) out[i] = boff[blockIdx.x] + lds[t] - v;
}

__global__ __launch_bounds__(256) void k_scatter_bkt(
    const int* __restrict__ src, const int* __restrict__ dst,
    const int* __restrict__ O, int* __restrict__ ebuf, int E, int NBK) {
  __shared__ int cur[256];
  if (threadIdx.x < NBK) cur[threadIdx.x] = O[threadIdx.x * NCH + blockIdx.x];
  __syncthreads();
  int chunk = (E + NCH - 1) / NCH;
  int lo = blockIdx.x * chunk, hi = min(lo + chunk, E);
  for (int e = lo + threadIdx.x; e < hi; e += 256) {
    int d = dst[e];
    int pos = atomicAdd(&cur[d >> 8], 1);
    ebuf[pos] = src[e] | ((d & 255) << 24);   // requires n < 2^24
  }
}

__global__ __launch_bounds__(256) void k_fill2(
    const int* __restrict__ ebuf, const int* __restrict__ O,
    int* __restrict__ eidx, int* __restrict__ rowptr,
    float* __restrict__ dinv, float* __restrict__ invcnt,
    int E, int n, int NBK) {
  __shared__ int hist[256];
  __shared__ int sc[256];
  __shared__ int cur[256];
  const int b = blockIdx.x;
  const int t = threadIdx.x;
  const int lo = O[b * NCH];
  const int hi = (b + 1 < NBK) ? O[(b + 1) * NCH] : E;
  hist[t] = 0;
  __syncthreads();
  for (int e = lo + t; e < hi; e += 256)
    atomicAdd(&hist[(ebuf[e] >> 24) & 255], 1);
  __syncthreads();
  int v = hist[t];
  sc[t] = v;
  __syncthreads();
  for (int ofs = 1; ofs < 256; ofs <<= 1) {
    int u = (t >= ofs) ? sc[t - ofs] : 0;
    __syncthreads();
    sc[t] += u;
    __syncthreads();
  }
  int excl = sc[t] - v;
  cur[t] = lo + excl;
  int node = b * 256 + t;
  if (node < n) {
    rowptr[node] = lo + excl;
    float d = (float)v;
    dinv[node]   = rsqrtf(d + 1.0f);
    invcnt[node] = 1.0f / fmaxf(d, 1.0f);
  }
  if (node == n || (b == NBK - 1 && t == 255)) rowptr[n] = E;
  __syncthreads();
  for (int e = lo + t; e < hi; e += 256) {
    int p = ebuf[e];
    int pos = atomicAdd(&cur[(p >> 24) & 255], 1);
    eidx[pos] = p & 0xFFFFFF;
  }
}

// =======================================================================
// CSR gather aggregation over bf16 rows (one wave per node)
// eidx preloaded 64-wide + shfl-broadcast: row loads have no dependent chain.
// GCN:  Hs = dinv[r]*h[r]. o = bias + dinv[v]*(sum_e Hs[s] + Hs[v])
// ADD:  o = scale[v]*sum_e Hs[s] + addf[v]
// else: o = scale[v]*sum_e Hs[s]
// =======================================================================
template<int F, bool GCN, bool OUTBF, bool ADD>
__global__ __launch_bounds__(256) void k_gather(
    const unsigned short* __restrict__ Hs, const float* __restrict__ scale,
    const int* __restrict__ rowptr, const int* __restrict__ eidx,
    const float* __restrict__ bias, const float* __restrict__ addf,
    float* __restrict__ outf, unsigned short* __restrict__ outb, int n) {
  constexpr int COLS = F / 8;       // lanes per edge (8 bf16 = 16 B each)
  constexpr int EPI  = 64 / COLS;   // edges per iteration
  const int v = blockIdx.x * 4 + (threadIdx.x >> 6);
  if (v >= n) return;
  const int lane = threadIdx.x & 63;
  const int col  = lane % COLS;
  const int eo   = lane / COLS;

  const int lo = rowptr[v], hi = rowptr[v + 1];
  float a[8] = {0.f,0.f,0.f,0.f,0.f,0.f,0.f,0.f};
  int myE = (lo + lane < hi) ? eidx[lo + lane] : 0;
  for (int base = lo; base < hi; base += 64) {
    int cnt = min(hi - base, 64);
    int nxt = (base + 64 + lane < hi) ? eidx[base + 64 + lane] : 0;
#pragma unroll 4
    for (int t = eo; t < cnt; t += EPI) {
      int s = __shfl(myE, t, 64);
      uint4 hv = *(const uint4*)&Hs[(long long)s * F + col * 8];
      float2 p0 = bfunpack(hv.x), p1 = bfunpack(hv.y);
      float2 p2 = bfunpack(hv.z), p3 = bfunpack(hv.w);
      a[0]+=p0.x; a[1]+=p0.y; a[2]+=p1.x; a[3]+=p1.y;
      a[4]+=p2.x; a[5]+=p2.y; a[6]+=p3.x; a[7]+=p3.y;
    }
    myE = nxt;
  }
#pragma unroll
  for (int m = COLS; m < 64; m <<= 1) {
#pragma unroll
    for (int j = 0; j < 8; j++) a[j] += __shfl_xor(a[j], m, 64);
  }
  if (eo == 0) {
    float sv = scale[v];
    float o[8];
    if constexpr (GCN) {
      uint4 hv = *(const uint4*)&Hs[(long long)v * F + col * 8];
      float2 p0 = bfunpack(hv.x), p1 = bfunpack(hv.y);
      float2 p2 = bfunpack(hv.z), p3 = bfunpack(hv.w);
      float h[8] = {p0.x,p0.y,p1.x,p1.y,p2.x,p2.y,p3.x,p3.y};
#pragma unroll
      for (int j = 0; j < 8; j++) o[j] = bias[col * 8 + j] + sv * (a[j] + h[j]);
    } else if constexpr (ADD) {
      const float4 t0 = *(const float4*)&addf[(long long)v * F + col * 8];
      const float4 t1 = *(const float4*)&addf[(long long)v * F + col * 8 + 4];
      o[0]=fmaf(sv,a[0],t0.x); o[1]=fmaf(sv,a[1],t0.y);
      o[2]=fmaf(sv,a[2],t0.z); o[3]=fmaf(sv,a[3],t0.w);
      o[4]=fmaf(sv,a[4],t1.x); o[5]=fmaf(sv,a[5],t1.y);
      o[6]=fmaf(sv,a[6],t1.z); o[7]=fmaf(sv,a[7],t1.w);
    } else {
#pragma unroll
      for (int j = 0; j < 8; j++) o[j] = sv * a[j];
    }
    if constexpr (OUTBF) {
      uint4 u;
      u.x = bfpack(o[0], o[1]); u.y = bfpack(o[2], o[3]);
      u.z = bfpack(o[4], o[5]); u.w = bfpack(o[6], o[7]);
      *(uint4*)&outb[(long long)v * F + col * 8] = u;
    } else {
      float4 o0 = {o[0],o[1],o[2],o[3]}, o1 = {o[4],o[5],o[6],o[7]};
      *(float4*)&outf[(long long)v * F + col * 8]     = o0;
      *(float4*)&outf[(long long)v * F + col * 8 + 4] = o1;
    }
  }
}

// ==== GEMM: Y = bf16(prescale*(act(X1)@Wa)); optional fused BN+lrelu on X1 ==
// BNIN: X1 is bf16 pre-BN; apply y=sc*x+sh, lrelu while staging (stats in LDS)
template<int K, int FOUT, int KC, int R, bool X1BF, bool BNIN>
__global__ __launch_bounds__(256) void k_gemm(
    const void* __restrict__ X1v, const float* __restrict__ Wa,
    const float* __restrict__ bnstats, const float* __restrict__ prescale,
    unsigned short* __restrict__ Yb, int n) {
  constexpr int TPR  = FOUT / 4;
  constexpr int RGN  = 256 / TPR;
  constexpr int ROWS = RGN * R;
  __shared__ float sX1[ROWS * K];
  __shared__ float sWa[KC * FOUT];
  __shared__ float sbn[BNIN ? 2 * K : 1];

  if constexpr (BNIN) {
    for (int i = threadIdx.x; i < 2 * K; i += 256) sbn[i] = bnstats[i];
    __syncthreads();
  }
  const int row0 = blockIdx.x * ROWS;
  if constexpr (X1BF) {
    const unsigned short* X1 = (const unsigned short*)X1v;
    for (int i = threadIdx.x; i < ROWS * K / 8; i += 256) {
      int r = i / (K / 8), k8 = (i % (K / 8)) * 8;
      int gr = row0 + r;
      uint4 raw = {0,0,0,0};
      if (gr < n) raw = *(const uint4*)&X1[(long long)gr * K + k8];
      float2 p0 = bfunpack(raw.x), p1 = bfunpack(raw.y);
      float2 p2 = bfunpack(raw.z), p3 = bfunpack(raw.w);
      float y[8] = {p0.x,p0.y,p1.x,p1.y,p2.x,p2.y,p3.x,p3.y};
      if constexpr (BNIN) {
#pragma unroll
        for (int j = 0; j < 8; j++) {
          float t = fmaf(y[j], sbn[k8 + j], sbn[K + k8 + j]);
          y[j] = (t >= 0.f) ? t : LEAK * t;
        }
      }
      float4 lo = {y[0],y[1],y[2],y[3]}, hi = {y[4],y[5],y[6],y[7]};
      *(float4*)&sX1[r * K + k8]     = lo;
      *(float4*)&sX1[r * K + k8 + 4] = hi;
    }
  } else {
    const float* X1 = (const float*)X1v;
    for (int i = threadIdx.x; i < ROWS * K / 4; i += 256) {
      int r = i / (K / 4), k4 = (i % (K / 4)) * 4;
      int gr = row0 + r;
      float4 vv = {0,0,0,0};
      if (gr < n) vv = *(const float4*)&X1[(long long)gr * K + k4];
      *(float4*)&sX1[r * K + k4] = vv;
    }
  }

  const int cg = threadIdx.x % TPR;
  const int rg = threadIdx.x / TPR;
  const int jc = cg * 4;
  float4 acc[R];
#pragma unroll
  for (int i = 0; i < R; i++) acc[i] = {0.f,0.f,0.f,0.f};

  for (int k0 = 0; k0 < K; k0 += KC) {
    __syncthreads();
    for (int i = threadIdx.x; i < KC * FOUT / 4; i += 256) {
      int kk = i / (FOUT / 4), j4 = (i % (FOUT / 4)) * 4;
      *(float4*)&sWa[kk * FOUT + j4] = *(const float4*)&Wa[(long long)(k0 + kk) * FOUT + j4];
    }
    __syncthreads();
#pragma unroll 8
    for (int kk = 0; kk < KC; kk++) {
      const float4 w = *(const float4*)&sWa[kk * FOUT + jc];
#pragma unroll
      for (int i = 0; i < R; i++) {
        float xv = sX1[(rg * R + i) * K + k0 + kk];
        acc[i].x = fmaf(xv, w.x, acc[i].x); acc[i].y = fmaf(xv, w.y, acc[i].y);
        acc[i].z = fmaf(xv, w.z, acc[i].z); acc[i].w = fmaf(xv, w.w, acc[i].w);
      }
    }
  }
#pragma unroll
  for (int i = 0; i < R; i++) {
    int gr = row0 + rg * R + i;
    if (gr >= n) continue;
    float4 o = acc[i];
    float ps = prescale ? prescale[gr] : 1.0f;
    uint2 u;
    u.x = bfpack(o.x * ps, o.y * ps);
    u.y = bfpack(o.z * ps, o.w * ps);
    *(uint2*)&Yb[(long long)gr * FOUT + jc] = u;
  }
}

// ==== SAGE dual GEMM (BN+lrelu fused on input): t1=X'@Wl bf16, t2=X'@Wr+bl f32
template<int R>
__global__ __launch_bounds__(256) void k_gemm_sage(
    const unsigned short* __restrict__ X, const float* __restrict__ Wl,
    const float* __restrict__ Wr, const float* __restrict__ bl,
    const float* __restrict__ bnstats,
    unsigned short* __restrict__ t1, float* __restrict__ t2, int n) {
  constexpr int K = 128, F = 64, KC = 64;
  constexpr int TPR = F / 4;          // 16
  constexpr int RGN = 256 / TPR;      // 16
  constexpr int ROWS = RGN * R;       // 32 for R=2
  __shared__ float sX[ROWS * K];
  __shared__ float sWl[KC * F];
  __shared__ float sWr[KC * F];
  __shared__ float sbn[2 * K];

  for (int i = threadIdx.x; i < 2 * K; i += 256) sbn[i] = bnstats[i];
  __syncthreads();
  const int row0 = blockIdx.x * ROWS;
  for (int i = threadIdx.x; i < ROWS * K / 8; i += 256) {
    int r = i / (K / 8), k8 = (i % (K / 8)) * 8;
    int gr = row0 + r;
    uint4 raw = {0,0,0,0};
    if (gr < n) raw = *(const uint4*)&X[(long long)gr * K + k8];
    float2 p0 = bfunpack(raw.x), p1 = bfunpack(raw.y);
    float2 p2 = bfunpack(raw.z), p3 = bfunpack(raw.w);
    float y[8] = {p0.x,p0.y,p1.x,p1.y,p2.x,p2.y,p3.x,p3.y};
#pragma unroll
    for (int j = 0; j < 8; j++) {
      float t = fmaf(y[j], sbn[k8 + j], sbn[K + k8 + j]);
      y[j] = (t >= 0.f) ? t : LEAK * t;
    }
    float4 lo = {y[0],y[1],y[2],y[3]}, hi = {y[4],y[5],y[6],y[7]};
    *(float4*)&sX[r * K + k8]     = lo;
    *(float4*)&sX[r * K + k8 + 4] = hi;
  }

  const int cg = threadIdx.x % TPR;
  const int rg = threadIdx.x / TPR;
  const int jc = cg * 4;
  float4 a1[R], a2[R];
#pragma unroll
  for (int i = 0; i < R; i++) { a1[i] = {0,0,0,0}; a2[i] = {0,0,0,0}; }

  for (int k0 = 0; k0 < K; k0 += KC) {
    __syncthreads();
    for (int i = threadIdx.x; i < KC * F / 4; i += 256) {
      int kk = i / (F / 4), j4 = (i % (F / 4)) * 4;
      *(float4*)&sWl[kk * F + j4] = *(const float4*)&Wl[(long long)(k0 + kk) * F + j4];
      *(float4*)&sWr[kk * F + j4] = *(const float4*)&Wr[(long long)(k0 + kk) * F + j4];
    }
    __syncthreads();
#pragma unroll 8
    for (int kk = 0; kk < KC; kk++) {
      const float4 wl = *(const float4*)&sWl[kk * F + jc];
      const float4 wr = *(const float4*)&sWr[kk * F + jc];
#pragma unroll
      for (int i = 0; i < R; i++) {
        float xv = sX[(rg * R + i) * K + k0 + kk];
        a1[i].x = fmaf(xv, wl.x, a1[i].x); a1[i].y = fmaf(xv, wl.y, a1[i].y);
        a1[i].z = fmaf(xv, wl.z, a1[i].z); a1[i].w = fmaf(xv, wl.w, a1[i].w);
        a2[i].x = fmaf(xv, wr.x, a2[i].x); a2[i].y = fmaf(xv, wr.y, a2[i].y);
        a2[i].z = fmaf(xv, wr.z, a2[i].z); a2[i].w = fmaf(xv, wr.w, a2[i].w);
      }
    }
  }
#pragma unroll
  for (int i = 0; i < R; i++) {
    int gr = row0 + rg * R + i;
    if (gr >= n) continue;
    uint2 u;
    u.x = bfpack(a1[i].x, a1[i].y);
    u.y = bfpack(a1[i].z, a1[i].w);
    *(uint2*)&t1[(long long)gr * F + jc] = u;
    float4 o = a2[i];
    o.x += bl[jc]; o.y += bl[jc+1]; o.z += bl[jc+2]; o.w += bl[jc+3];
    *(float4*)&t2[(long long)gr * F + jc] = o;
  }
}

// ---------------- BatchNorm stats (from bf16 pre-BN buffer) ----------------
template<int F>
__global__ __launch_bounds__(256) void k_bn_stats(const unsigned short* __restrict__ Y,
                                                  float* __restrict__ partials, int n) {
  constexpr int FP  = F / 2;
  constexpr int RPB = 256 / FP;
  const int f2 = threadIdx.x % FP;
  const int r0 = threadIdx.x / FP;
  const unsigned* Yu = (const unsigned*)Y;
  float s1a = 0.f, s2a = 0.f, s1b = 0.f, s2b = 0.f;
  for (long long r = (long long)blockIdx.x * RPB + r0; r < n; r += 256LL * RPB) {
    float2 p = bfunpack(Yu[r * FP + f2]);
    s1a += p.x; s2a += p.x * p.x;
    s1b += p.y; s2b += p.y * p.y;
  }
  __shared__ float l1a[256], l2a[256], l1b[256], l2b[256];
  l1a[threadIdx.x] = s1a; l2a[threadIdx.x] = s2a;
  l1b[threadIdx.x] = s1b; l2b[threadIdx.x] = s2b;
  __syncthreads();
  if (r0 == 0) {
#pragma unroll
    for (int i = 1; i < RPB; i++) {
      s1a += l1a[i * FP + f2]; s2a += l2a[i * FP + f2];
      s1b += l1b[i * FP + f2]; s2b += l2b[i * FP + f2];
    }
    float* p = &partials[blockIdx.x * 2 * F];
    p[2 * f2]         = s1a;
    p[2 * f2 + 1]     = s1b;
    p[F + 2 * f2]     = s2a;
    p[F + 2 * f2 + 1] = s2b;
  }
}

__global__ void k_bn_finalize(const float* __restrict__ partials, float* __restrict__ stats,
                              const float* __restrict__ g, const float* __restrict__ be,
                              int F, float invN) {
  int f = threadIdx.x;
  if (f >= F) return;
  float s1 = 0.f, s2 = 0.f;
  for (int b = 0; b < 256; b++) {
    s1 += partials[b * 2 * F + f];
    s2 += partials[b * 2 * F + F + f];
  }
  float m   = s1 * invN;
  float var = s2 * invN - m * m;
  float sc  = g[f] * rsqrtf(var + BNEPS);
  stats[f]     = sc;
  stats[F + f] = be[f] - m * sc;
}

// ---------------- pool (batch sorted; binary search per graph) + link ------
__global__ __launch_bounds__(256) void k_pool2(const float* __restrict__ a4,
                                               const int* __restrict__ batch,
                                               float* __restrict__ gpool, int n) {
  int g = blockIdx.x * 4 + (threadIdx.x >> 6);
  if (g >= NGMAX) return;
  int lane = threadIdx.x & 63;
  // lower_bound(batch, g), lower_bound(batch, g+1)
  int s = 0, e = n;
  while (s < e) { int m = (s + e) >> 1; if (batch[m] < g) s = m + 1; else e = m; }
  int s2 = s, e2 = n;
  while (s2 < e2) { int m = (s2 + e2) >> 1; if (batch[m] < g + 1) s2 = m + 1; else e2 = m; }
  int f = lane & 31, ro = lane >> 5;
  float acc = 0.f;
  for (int r = s + ro; r < s2; r += 2) acc += a4[(long long)r * 32 + f];
  acc += __shfl_xor(acc, 32, 64);
  if (lane < 32) gpool[(long long)g * 32 + f] = acc;
}

__global__ void k_link(const float* __restrict__ g, const int* __restrict__ li0,
                       const int* __restrict__ li1, float* __restrict__ out, int L) {
  int i = blockIdx.x * blockDim.x + threadIdx.x;
  if (i >= L) return;
  const float* a = g + (long long)li0[i] * 32;
  const float* b = g + (long long)li1[i] * 32;
  float s = 0.f;
#pragma unroll
  for (int f = 0; f < 32; f++) s = fmaf(a[f], b[f], s);
  out[i] = 1.0f / (1.0f + expf(-s));
}

// ---------------- launch ----------------
extern "C" void kernel_launch(void* const* d_in, const int* in_sizes, int n_in,
                              void* d_out, int out_size, void* d_ws, size_t ws_size,
                              hipStream_t stream) {
  const float* x   = (const float*)d_in[0];
  const int* ei    = (const int*)d_in[1];
  const int* batch = (const int*)d_in[2];
  const int* li    = (const int*)d_in[3];
  const float* W1  = (const float*)d_in[5];
  const float* b1  = (const float*)d_in[6];
  const float* g1  = (const float*)d_in[7];
  const float* be1 = (const float*)d_in[8];
  const float* Wl2 = (const float*)d_in[9];
  const float* bl2 = (const float*)d_in[10];
  const float* Wr2 = (const float*)d_in[11];
  const float* g2  = (const float*)d_in[12];
  const float* be2 = (const float*)d_in[13];
  const float* W3  = (const float*)d_in[14];
  const float* b3  = (const float*)d_in[15];
  const float* g3  = (const float*)d_in[16];
  const float* be3 = (const float*)d_in[17];
  const float* W4  = (const float*)d_in[18];
  const float* b4  = (const float*)d_in[19];

  const int n = in_sizes[0] / 128;   // 50000
  const int E = in_sizes[1] / 2;     // 800000
  const int L = in_sizes[3] / 2;     // 1000
  const int* src = ei;
  const int* dst = ei + E;
  const int* li0 = li;
  const int* li1 = li + L;
  const int NBK = (n + 255) / 256;   // dst buckets (<=256 for n<=65536)

  char* base = (char*)d_ws;
  size_t off = 0;
  auto alloc = [&](size_t bytes) -> void* {
    void* p = (void*)(base + off);
    off = (off + bytes + 255) & ~(size_t)255;
    return p;
  };
  int*   H      = (int*)alloc((size_t)NBK * NCH * 4);
  int*   O      = (int*)alloc((size_t)NBK * NCH * 4);
  int*   hsum   = (int*)alloc(1024 * 4);
  int*   ebuf   = (int*)alloc((size_t)E * 4);
  int*   eidx   = (int*)alloc((size_t)E * 4);
  int*   rowptr = (int*)alloc((size_t)(n + 1) * 4);
  float* dinv   = (float*)alloc((size_t)n * 4);
  float* invcnt = (float*)alloc((size_t)n * 4);
  float* stats1 = (float*)alloc(256 * 4);
  float* stats2 = (float*)alloc(128 * 4);
  float* stats3 = (float*)alloc(64 * 4);
  float* partials = (float*)alloc((size_t)256 * 256 * 4);
  float* gpool  = (float*)alloc((size_t)NGMAX * 32 * 4);
  unsigned short* h1b  = (unsigned short*)alloc((size_t)n * 128 * 2); // dinv*(x@W1)
  unsigned short* a1b  = (unsigned short*)alloc((size_t)n * 128 * 2); // pre-BN a1
  unsigned short* t1b  = (unsigned short*)alloc((size_t)n * 64 * 2);  // h1'@Wl2
  float*          t2f  = (float*)alloc((size_t)n * 64 * 4);           // h1'@Wr2+bl2
  unsigned short* h2b  = (unsigned short*)alloc((size_t)n * 64 * 2);  // pre-BN h2
  unsigned short* h3gb = (unsigned short*)alloc((size_t)n * 32 * 2);  // dinv*(h2'@W3)
  unsigned short* a3b  = (unsigned short*)alloc((size_t)n * 32 * 2);  // pre-BN a3
  unsigned short* h4b  = (unsigned short*)alloc((size_t)n * 32 * 2);  // dinv*(h3'@W4)
  float*          a4f  = (float*)alloc((size_t)n * 32 * 4);           // a4 (fp32)
  (void)ws_size; (void)n_in; (void)out_size;

  const int BT = 256;
  auto cdiv = [](long long a, long long b) { return (int)((a + b - 1) / b); };
  const int GB  = cdiv(n, 4);                 // gather grid
  const int MH  = NBK * NCH;                  // histogram elements
  const int NBH = cdiv(MH, 256);              // scan blocks

  // ---- CSR build: bucketed counting sort ----
  k_hist<<<NCH, 256, 0, stream>>>(dst, H, E, NBK);
  k_gscan1<<<NBH, 256, 0, stream>>>(H, hsum, MH);
  k_gscan2<<<1, 256, 0, stream>>>(hsum, NBH);
  k_gscan3<<<NBH, 256, 0, stream>>>(H, hsum, O, MH);
  k_scatter_bkt<<<NCH, 256, 0, stream>>>(src, dst, O, ebuf, E, NBK);
  k_fill2<<<NBK, 256, 0, stream>>>(ebuf, O, eidx, rowptr, dinv, invcnt, E, n, NBK);

  // ---- L1: GCN 128->128 ----
  k_gemm<128,128,64,4,false,false><<<cdiv(n,32), 256, 0, stream>>>(
      x, W1, nullptr, dinv, h1b, n);
  k_gather<128,true,true,false><<<GB, 256, 0, stream>>>(
      h1b, dinv, rowptr, eidx, b1, nullptr, nullptr, a1b, n);
  k_bn_stats<128><<<256, 256, 0, stream>>>(a1b, partials, n);
  k_bn_finalize<<<1, 128, 0, stream>>>(partials, stats1, g1, be1, 128, 1.0f / n);

  // ---- L2: SAGE 128->64 (BN1+lrelu fused into staging) ----
  k_gemm_sage<2><<<cdiv(n,32), 256, 0, stream>>>(a1b, Wl2, Wr2, bl2, stats1, t1b, t2f, n);
  k_gather<64,false,true,true><<<GB, 256, 0, stream>>>(
      t1b, invcnt, rowptr, eidx, nullptr, t2f, nullptr, h2b, n);
  k_bn_stats<64><<<256, 256, 0, stream>>>(h2b, partials, n);
  k_bn_finalize<<<1, 64, 0, stream>>>(partials, stats2, g2, be2, 64, 1.0f / n);

  // ---- L3: GCN 64->32 (BN2+lrelu fused) ----
  k_gemm<64,32,64,4,true,true><<<cdiv(n,128), 256, 0, stream>>>(
      h2b, W3, stats2, dinv, h3gb, n);
  k_gather<32,true,true,false><<<GB, 256, 0, stream>>>(
      h3gb, dinv, rowptr, eidx, b3, nullptr, nullptr, a3b, n);
  k_bn_stats<32><<<256, 256, 0, stream>>>(a3b, partials, n);
  k_bn_finalize<<<1, 32, 0, stream>>>(partials, stats3, g3, be3, 32, 1.0f / n);

  // ---- L4: GCN 32->32 (BN3+lrelu fused), fp32 out ----
  k_gemm<32,32,32,4,true,true><<<cdiv(n,128), 256, 0, stream>>>(
      a3b, W4, stats3, dinv, h4b, n);
  k_gather<32,true,false,false><<<GB, 256, 0, stream>>>(
      h4b, dinv, rowptr, eidx, b4, nullptr, a4f, nullptr, n);

  // ---- pool (no atomics; batch sorted) + link ----
  k_pool2<<<NGMAX / 4, 256, 0, stream>>>(a4f, batch, gpool, n);
  k_link<<<cdiv(L, BT), BT, 0, stream>>>(gpool, li0, li1, (float*)d_out, L);
}

// Round 8
// 380.974 us; speedup vs baseline: 9.8895x; 1.0777x over previous
//
#include <hip/hip_runtime.h>
#include <math.h>

#define LEAK 0.01f
#define BNEPS 1e-5f
#define NCH 256   // chunks for hist/scatter phases
#define NGMAX 1024

typedef __attribute__((ext_vector_type(8))) short bf16x8;
typedef __attribute__((ext_vector_type(4))) float f32x4;

// ---------------- bf16 helpers ----------------
__device__ inline unsigned bfpack(float a, float b) {  // two f32 -> packed bf16 (RNE)
  unsigned ua = __float_as_uint(a);
  unsigned ub = __float_as_uint(b);
  unsigned ra = (ua + 0x7fffu + ((ua >> 16) & 1u)) >> 16;
  unsigned rb = (ub + 0x7fffu + ((ub >> 16) & 1u)) & 0xffff0000u;
  return ra | rb;
}
__device__ inline unsigned short bfround(float a) {
  unsigned ua = __float_as_uint(a);
  return (unsigned short)((ua + 0x7fffu + ((ua >> 16) & 1u)) >> 16);
}
__device__ inline float2 bfunpack(unsigned u) {
  float2 r;
  r.x = __uint_as_float(u << 16);
  r.y = __uint_as_float(u & 0xffff0000u);
  return r;
}

// =======================================================================
// CSR build via bucketed counting sort (bucket = dst>>8, NBK<=256)
// =======================================================================
__global__ __launch_bounds__(256) void k_hist(const int* __restrict__ dst,
                                              int* __restrict__ H, int E, int NBK) {
  __shared__ int h[256];
  h[threadIdx.x] = 0;
  __syncthreads();
  int chunk = (E + NCH - 1) / NCH;
  int lo = blockIdx.x * chunk, hi = min(lo + chunk, E);
  for (int e = lo + threadIdx.x; e < hi; e += 256)
    atomicAdd(&h[dst[e] >> 8], 1);
  __syncthreads();
  if (threadIdx.x < NBK) H[threadIdx.x * NCH + blockIdx.x] = h[threadIdx.x];
}

__global__ __launch_bounds__(256) void k_gscan1(const int* __restrict__ in,
                                                int* __restrict__ bsum, int m) {
  int i = blockIdx.x * 256 + threadIdx.x;
  int v = (i < m) ? in[i] : 0;
#pragma unroll
  for (int s = 1; s < 64; s <<= 1) v += __shfl_xor(v, s, 64);
  __shared__ int ws[4];
  if ((threadIdx.x & 63) == 0) ws[threadIdx.x >> 6] = v;
  __syncthreads();
  if (threadIdx.x == 0) bsum[blockIdx.x] = ws[0] + ws[1] + ws[2] + ws[3];
}
__global__ __launch_bounds__(256) void k_gscan2(int* __restrict__ bsum, int NB) {
  __shared__ int lds[256];
  int t = threadIdx.x;
  int v = (t < NB) ? bsum[t] : 0;
  lds[t] = v;
  __syncthreads();
  for (int ofs = 1; ofs < 256; ofs <<= 1) {
    int u = (t >= ofs) ? lds[t - ofs] : 0;
    __syncthreads();
    lds[t] += u;
    __syncthreads();
  }
  if (t < NB) bsum[t] = lds[t] - v;  // exclusive, in-place
}
__global__ __launch_bounds__(256) void k_gscan3(const int* __restrict__ in,
                                                const int* __restrict__ boff,
                                                int* __restrict__ out, int m) {
  __shared__ int lds[256];
  int t = threadIdx.x;
  int i = blockIdx.x * 256 + t;
  int v = (i < m) ? in[i] : 0;
  lds[t] = v;
  __syncthreads();
  for (int ofs = 1; ofs < 256; ofs <<= 1) {
    int u = (t >= ofs) ? lds[t - ofs] : 0;
    __syncthreads();
    lds[t] += u;
    __syncthreads();
  }
  if (i < m) out[i] = boff[blockIdx.x] + lds[t] - v;
}

__global__ __launch_bounds__(256) void k_scatter_bkt(
    const int* __restrict__ src, const int* __restrict__ dst,
    const int* __restrict__ O, int* __restrict__ ebuf, int E, int NBK) {
  __shared__ int cur[256];
  if (threadIdx.x < NBK) cur[threadIdx.x] = O[threadIdx.x * NCH + blockIdx.x];
  __syncthreads();
  int chunk = (E + NCH - 1) / NCH;
  int lo = blockIdx.x * chunk, hi = min(lo + chunk, E);
  for (int e = lo + threadIdx.x; e < hi; e += 256) {
    int d = dst[e];
    int pos = atomicAdd(&cur[d >> 8], 1);
    ebuf[pos] = src[e] | ((d & 255) << 24);   // requires n < 2^24
  }
}

__global__ __launch_bounds__(256) void k_fill2(
    const int* __restrict__ ebuf, const int* __restrict__ O,
    int* __restrict__ eidx, int* __restrict__ rowptr,
    float* __restrict__ dinv, float* __restrict__ invcnt,
    int E, int n, int NBK) {
  __shared__ int hist[256];
  __shared__ int sc[256];
  __shared__ int cur[256];
  const int b = blockIdx.x;
  const int t = threadIdx.x;
  const int lo = O[b * NCH];
  const int hi = (b + 1 < NBK) ? O[(b + 1) * NCH] : E;
  hist[t] = 0;
  __syncthreads();
  for (int e = lo + t; e < hi; e += 256)
    atomicAdd(&hist[(ebuf[e] >> 24) & 255], 1);
  __syncthreads();
  int v = hist[t];
  sc[t] = v;
  __syncthreads();
  for (int ofs = 1; ofs < 256; ofs <<= 1) {
    int u = (t >= ofs) ? sc[t - ofs] : 0;
    __syncthreads();
    sc[t] += u;
    __syncthreads();
  }
  int excl = sc[t] - v;
  cur[t] = lo + excl;
  int node = b * 256 + t;
  if (node < n) {
    rowptr[node] = lo + excl;
    float d = (float)v;
    dinv[node]   = rsqrtf(d + 1.0f);
    invcnt[node] = 1.0f / fmaxf(d, 1.0f);
  }
  if (node == n || (b == NBK - 1 && t == 255)) rowptr[n] = E;
  __syncthreads();
  for (int e = lo + t; e < hi; e += 256) {
    int p = ebuf[e];
    int pos = atomicAdd(&cur[(p >> 24) & 255], 1);
    eidx[pos] = p & 0xFFFFFF;
  }
}

// =======================================================================
// CSR gather aggregation over bf16 rows (one wave per node)
// =======================================================================
template<int F, bool GCN, bool OUTBF, bool ADD>
__global__ __launch_bounds__(256) void k_gather(
    const unsigned short* __restrict__ Hs, const float* __restrict__ scale,
    const int* __restrict__ rowptr, const int* __restrict__ eidx,
    const float* __restrict__ bias, const float* __restrict__ addf,
    float* __restrict__ outf, unsigned short* __restrict__ outb, int n) {
  constexpr int COLS = F / 8;       // lanes per edge (8 bf16 = 16 B each)
  constexpr int EPI  = 64 / COLS;   // edges per iteration
  const int v = blockIdx.x * 4 + (threadIdx.x >> 6);
  if (v >= n) return;
  const int lane = threadIdx.x & 63;
  const int col  = lane % COLS;
  const int eo   = lane / COLS;

  const int lo = rowptr[v], hi = rowptr[v + 1];
  float a[8] = {0.f,0.f,0.f,0.f,0.f,0.f,0.f,0.f};
  int myE = (lo + lane < hi) ? eidx[lo + lane] : 0;
  for (int base = lo; base < hi; base += 64) {
    int cnt = min(hi - base, 64);
    int nxt = (base + 64 + lane < hi) ? eidx[base + 64 + lane] : 0;
#pragma unroll 4
    for (int t = eo; t < cnt; t += EPI) {
      int s = __shfl(myE, t, 64);
      uint4 hv = *(const uint4*)&Hs[(long long)s * F + col * 8];
      float2 p0 = bfunpack(hv.x), p1 = bfunpack(hv.y);
      float2 p2 = bfunpack(hv.z), p3 = bfunpack(hv.w);
      a[0]+=p0.x; a[1]+=p0.y; a[2]+=p1.x; a[3]+=p1.y;
      a[4]+=p2.x; a[5]+=p2.y; a[6]+=p3.x; a[7]+=p3.y;
    }
    myE = nxt;
  }
#pragma unroll
  for (int m = COLS; m < 64; m <<= 1) {
#pragma unroll
    for (int j = 0; j < 8; j++) a[j] += __shfl_xor(a[j], m, 64);
  }
  if (eo == 0) {
    float sv = scale[v];
    float o[8];
    if constexpr (GCN) {
      uint4 hv = *(const uint4*)&Hs[(long long)v * F + col * 8];
      float2 p0 = bfunpack(hv.x), p1 = bfunpack(hv.y);
      float2 p2 = bfunpack(hv.z), p3 = bfunpack(hv.w);
      float h[8] = {p0.x,p0.y,p1.x,p1.y,p2.x,p2.y,p3.x,p3.y};
#pragma unroll
      for (int j = 0; j < 8; j++) o[j] = bias[col * 8 + j] + sv * (a[j] + h[j]);
    } else if constexpr (ADD) {
      const float4 t0 = *(const float4*)&addf[(long long)v * F + col * 8];
      const float4 t1 = *(const float4*)&addf[(long long)v * F + col * 8 + 4];
      o[0]=fmaf(sv,a[0],t0.x); o[1]=fmaf(sv,a[1],t0.y);
      o[2]=fmaf(sv,a[2],t0.z); o[3]=fmaf(sv,a[3],t0.w);
      o[4]=fmaf(sv,a[4],t1.x); o[5]=fmaf(sv,a[5],t1.y);
      o[6]=fmaf(sv,a[6],t1.z); o[7]=fmaf(sv,a[7],t1.w);
    } else {
#pragma unroll
      for (int j = 0; j < 8; j++) o[j] = sv * a[j];
    }
    if constexpr (OUTBF) {
      uint4 u;
      u.x = bfpack(o[0], o[1]); u.y = bfpack(o[2], o[3]);
      u.z = bfpack(o[4], o[5]); u.w = bfpack(o[6], o[7]);
      *(uint4*)&outb[(long long)v * F + col * 8] = u;
    } else {
      float4 o0 = {o[0],o[1],o[2],o[3]}, o1 = {o[4],o[5],o[6],o[7]};
      *(float4*)&outf[(long long)v * F + col * 8]     = o0;
      *(float4*)&outf[(long long)v * F + col * 8 + 4] = o1;
    }
  }
}

// =======================================================================
// MFMA GEMM: Yb = bf16(prescale * (act(X) @ W)), 16x16x32 bf16 MFMA.
// Block = 256 thr = 4 waves; 64-row tile; full F width; W^T staged bf16 in LDS.
// A frag: m=lane&15, k=quad*8+j (row-major sX).  B frag: n=lane&15, k=quad*8+j
// (sWT[n][k]).  C/D: col=lane&15, row=quad*4+reg.  [verified layouts, guide §3]
// =======================================================================
template<int K, int F, bool XBF, bool BNIN>
__global__ __launch_bounds__(256) void k_gemm_mfma(
    const void* __restrict__ Xv, const float* __restrict__ W,
    const float* __restrict__ bnstats, const float* __restrict__ prescale,
    unsigned short* __restrict__ Yb, int n) {
  constexpr int SP  = K + 8;      // padded LDS row stride (shorts)
  constexpr int NCT = F / 16;     // col-tiles per wave
  __shared__ unsigned short sX[64 * SP];
  __shared__ unsigned short sWT[F * SP];
  __shared__ float sbn[BNIN ? 2 * K : 1];

  const int row0 = blockIdx.x * 64;
  if constexpr (BNIN) {
    for (int i = threadIdx.x; i < 2 * K; i += 256) sbn[i] = bnstats[i];
    __syncthreads();
  }
  // stage W^T (bf16): sWT[nn][kk]
  for (int i = threadIdx.x; i < (K / 2) * F; i += 256) {
    int nn = i % F;
    int kk = (i / F) * 2;
    float w0 = W[(long long)kk * F + nn];
    float w1 = W[(long long)(kk + 1) * F + nn];
    *(unsigned*)&sWT[nn * SP + kk] = bfpack(w0, w1);
  }
  // stage X rows (bf16, optional BN+lrelu)
  for (int i = threadIdx.x; i < 64 * (K / 8); i += 256) {
    int r = i / (K / 8), k8 = (i % (K / 8)) * 8;
    int gr = row0 + r;
    uint4 u = {0, 0, 0, 0};
    if (gr < n) {
      if constexpr (XBF) {
        const unsigned short* X = (const unsigned short*)Xv;
        uint4 raw = *(const uint4*)&X[(long long)gr * K + k8];
        if constexpr (BNIN) {
          float2 p0 = bfunpack(raw.x), p1 = bfunpack(raw.y);
          float2 p2 = bfunpack(raw.z), p3 = bfunpack(raw.w);
          float y[8] = {p0.x,p0.y,p1.x,p1.y,p2.x,p2.y,p3.x,p3.y};
#pragma unroll
          for (int j = 0; j < 8; j++) {
            float t = fmaf(y[j], sbn[k8 + j], sbn[K + k8 + j]);
            y[j] = (t >= 0.f) ? t : LEAK * t;
          }
          u.x = bfpack(y[0], y[1]); u.y = bfpack(y[2], y[3]);
          u.z = bfpack(y[4], y[5]); u.w = bfpack(y[6], y[7]);
        } else {
          u = raw;
        }
      } else {
        const float* X = (const float*)Xv;
        float4 xa = *(const float4*)&X[(long long)gr * K + k8];
        float4 xb = *(const float4*)&X[(long long)gr * K + k8 + 4];
        u.x = bfpack(xa.x, xa.y); u.y = bfpack(xa.z, xa.w);
        u.z = bfpack(xb.x, xb.y); u.w = bfpack(xb.z, xb.w);
      }
    }
    *(uint4*)&sX[r * SP + k8] = u;
  }
  __syncthreads();

  const int wv   = threadIdx.x >> 6;
  const int lane = threadIdx.x & 63;
  const int l16  = lane & 15;
  const int quad = lane >> 4;
  f32x4 acc[NCT];
#pragma unroll
  for (int c = 0; c < NCT; c++) acc[c] = (f32x4){0.f, 0.f, 0.f, 0.f};

#pragma unroll
  for (int k0 = 0; k0 < K; k0 += 32) {
    bf16x8 af = *(const bf16x8*)&sX[(wv * 16 + l16) * SP + k0 + quad * 8];
#pragma unroll
    for (int c = 0; c < NCT; c++) {
      bf16x8 bfr = *(const bf16x8*)&sWT[(c * 16 + l16) * SP + k0 + quad * 8];
      acc[c] = __builtin_amdgcn_mfma_f32_16x16x32_bf16(af, bfr, acc[c], 0, 0, 0);
    }
  }

  const int rbase = row0 + wv * 16 + quad * 4;
  float ps[4];
#pragma unroll
  for (int rg = 0; rg < 4; rg++) {
    int gr = rbase + rg;
    ps[rg] = (prescale && gr < n) ? prescale[gr] : 1.0f;
  }
#pragma unroll
  for (int c = 0; c < NCT; c++) {
    int col = c * 16 + l16;
#pragma unroll
    for (int rg = 0; rg < 4; rg++) {
      int gr = rbase + rg;
      if (gr < n) Yb[(long long)gr * F + col] = bfround(acc[c][rg] * ps[rg]);
    }
  }
}

// ==== SAGE dual MFMA GEMM (BN+lrelu fused): t1=X'@Wl bf16, t2=X'@Wr+bl f32 ==
__global__ __launch_bounds__(256) void k_gemm_sage_mfma(
    const unsigned short* __restrict__ X, const float* __restrict__ Wl,
    const float* __restrict__ Wr, const float* __restrict__ bl,
    const float* __restrict__ bnstats,
    unsigned short* __restrict__ t1, float* __restrict__ t2, int n) {
  constexpr int K = 128, F = 64, SP = K + 8, NCT = F / 16;  // 4
  __shared__ unsigned short sX[64 * SP];
  __shared__ unsigned short sWlT[F * SP];
  __shared__ unsigned short sWrT[F * SP];
  __shared__ float sbn[2 * K];

  for (int i = threadIdx.x; i < 2 * K; i += 256) sbn[i] = bnstats[i];
  __syncthreads();
  const int row0 = blockIdx.x * 64;
  for (int i = threadIdx.x; i < (K / 2) * F; i += 256) {
    int nn = i % F;
    int kk = (i / F) * 2;
    *(unsigned*)&sWlT[nn * SP + kk] =
        bfpack(Wl[(long long)kk * F + nn], Wl[(long long)(kk + 1) * F + nn]);
    *(unsigned*)&sWrT[nn * SP + kk] =
        bfpack(Wr[(long long)kk * F + nn], Wr[(long long)(kk + 1) * F + nn]);
  }
  for (int i = threadIdx.x; i < 64 * (K / 8); i += 256) {
    int r = i / (K / 8), k8 = (i % (K / 8)) * 8;
    int gr = row0 + r;
    uint4 u = {0, 0, 0, 0};
    if (gr < n) {
      uint4 raw = *(const uint4*)&X[(long long)gr * K + k8];
      float2 p0 = bfunpack(raw.x), p1 = bfunpack(raw.y);
      float2 p2 = bfunpack(raw.z), p3 = bfunpack(raw.w);
      float y[8] = {p0.x,p0.y,p1.x,p1.y,p2.x,p2.y,p3.x,p3.y};
#pragma unroll
      for (int j = 0; j < 8; j++) {
        float t = fmaf(y[j], sbn[k8 + j], sbn[K + k8 + j]);
        y[j] = (t >= 0.f) ? t : LEAK * t;
      }
      u.x = bfpack(y[0], y[1]); u.y = bfpack(y[2], y[3]);
      u.z = bfpack(y[4], y[5]); u.w = bfpack(y[6], y[7]);
    }
    *(uint4*)&sX[r * SP + k8] = u;
  }
  __syncthreads();

  const int wv   = threadIdx.x >> 6;
  const int lane = threadIdx.x & 63;
  const int l16  = lane & 15;
  const int quad = lane >> 4;
  f32x4 a1[NCT], a2[NCT];
#pragma unroll
  for (int c = 0; c < NCT; c++) {
    a1[c] = (f32x4){0.f, 0.f, 0.f, 0.f};
    a2[c] = (f32x4){0.f, 0.f, 0.f, 0.f};
  }
#pragma unroll
  for (int k0 = 0; k0 < K; k0 += 32) {
    bf16x8 af = *(const bf16x8*)&sX[(wv * 16 + l16) * SP + k0 + quad * 8];
#pragma unroll
    for (int c = 0; c < NCT; c++) {
      bf16x8 bl8 = *(const bf16x8*)&sWlT[(c * 16 + l16) * SP + k0 + quad * 8];
      bf16x8 br8 = *(const bf16x8*)&sWrT[(c * 16 + l16) * SP + k0 + quad * 8];
      a1[c] = __builtin_amdgcn_mfma_f32_16x16x32_bf16(af, bl8, a1[c], 0, 0, 0);
      a2[c] = __builtin_amdgcn_mfma_f32_16x16x32_bf16(af, br8, a2[c], 0, 0, 0);
    }
  }
  const int rbase = row0 + wv * 16 + quad * 4;
#pragma unroll
  for (int c = 0; c < NCT; c++) {
    int col = c * 16 + l16;
    float blv = bl[col];
#pragma unroll
    for (int rg = 0; rg < 4; rg++) {
      int gr = rbase + rg;
      if (gr < n) {
        t1[(long long)gr * F + col] = bfround(a1[c][rg]);
        t2[(long long)gr * F + col] = a2[c][rg] + blv;
      }
    }
  }
}

// ---------------- BatchNorm stats (from bf16 pre-BN buffer) ----------------
template<int F>
__global__ __launch_bounds__(256) void k_bn_stats(const unsigned short* __restrict__ Y,
                                                  float* __restrict__ partials, int n) {
  constexpr int FP  = F / 2;
  constexpr int RPB = 256 / FP;
  const int f2 = threadIdx.x % FP;
  const int r0 = threadIdx.x / FP;
  const unsigned* Yu = (const unsigned*)Y;
  float s1a = 0.f, s2a = 0.f, s1b = 0.f, s2b = 0.f;
  for (long long r = (long long)blockIdx.x * RPB + r0; r < n; r += 256LL * RPB) {
    float2 p = bfunpack(Yu[r * FP + f2]);
    s1a += p.x; s2a += p.x * p.x;
    s1b += p.y; s2b += p.y * p.y;
  }
  __shared__ float l1a[256], l2a[256], l1b[256], l2b[256];
  l1a[threadIdx.x] = s1a; l2a[threadIdx.x] = s2a;
  l1b[threadIdx.x] = s1b; l2b[threadIdx.x] = s2b;
  __syncthreads();
  if (r0 == 0) {
#pragma unroll
    for (int i = 1; i < RPB; i++) {
      s1a += l1a[i * FP + f2]; s2a += l2a[i * FP + f2];
      s1b += l1b[i * FP + f2]; s2b += l2b[i * FP + f2];
    }
    float* p = &partials[blockIdx.x * 2 * F];
    p[2 * f2]         = s1a;
    p[2 * f2 + 1]     = s1b;
    p[F + 2 * f2]     = s2a;
    p[F + 2 * f2 + 1] = s2b;
  }
}

__global__ void k_bn_finalize(const float* __restrict__ partials, float* __restrict__ stats,
                              const float* __restrict__ g, const float* __restrict__ be,
                              int F, float invN) {
  int f = threadIdx.x;
  if (f >= F) return;
  float s1 = 0.f, s2 = 0.f;
  for (int b = 0; b < 256; b++) {
    s1 += partials[b * 2 * F + f];
    s2 += partials[b * 2 * F + F + f];
  }
  float m   = s1 * invN;
  float var = s2 * invN - m * m;
  float sc  = g[f] * rsqrtf(var + BNEPS);
  stats[f]     = sc;
  stats[F + f] = be[f] - m * sc;
}

// ---------------- pool (batch sorted; binary search per graph) + link ------
__global__ __launch_bounds__(256) void k_pool2(const float* __restrict__ a4,
                                               const int* __restrict__ batch,
                                               float* __restrict__ gpool, int n) {
  int g = blockIdx.x * 4 + (threadIdx.x >> 6);
  if (g >= NGMAX) return;
  int lane = threadIdx.x & 63;
  int s = 0, e = n;
  while (s < e) { int m = (s + e) >> 1; if (batch[m] < g) s = m + 1; else e = m; }
  int s2 = s, e2 = n;
  while (s2 < e2) { int m = (s2 + e2) >> 1; if (batch[m] < g + 1) s2 = m + 1; else e2 = m; }
  int f = lane & 31, ro = lane >> 5;
  float acc = 0.f;
  for (int r = s + ro; r < s2; r += 2) acc += a4[(long long)r * 32 + f];
  acc += __shfl_xor(acc, 32, 64);
  if (lane < 32) gpool[(long long)g * 32 + f] = acc;
}

__global__ void k_link(const float* __restrict__ g, const int* __restrict__ li0,
                       const int* __restrict__ li1, float* __restrict__ out, int L) {
  int i = blockIdx.x * blockDim.x + threadIdx.x;
  if (i >= L) return;
  const float* a = g + (long long)li0[i] * 32;
  const float* b = g + (long long)li1[i] * 32;
  float s = 0.f;
#pragma unroll
  for (int f = 0; f < 32; f++) s = fmaf(a[f], b[f], s);
  out[i] = 1.0f / (1.0f + expf(-s));
}

// ---------------- launch ----------------
extern "C" void kernel_launch(void* const* d_in, const int* in_sizes, int n_in,
                              void* d_out, int out_size, void* d_ws, size_t ws_size,
                              hipStream_t stream) {
  const float* x   = (const float*)d_in[0];
  const int* ei    = (const int*)d_in[1];
  const int* batch = (const int*)d_in[2];
  const int* li    = (const int*)d_in[3];
  const float* W1  = (const float*)d_in[5];
  const float* b1  = (const float*)d_in[6];
  const float* g1  = (const float*)d_in[7];
  const float* be1 = (const float*)d_in[8];
  const float* Wl2 = (const float*)d_in[9];
  const float* bl2 = (const float*)d_in[10];
  const float* Wr2 = (const float*)d_in[11];
  const float* g2  = (const float*)d_in[12];
  const float* be2 = (const float*)d_in[13];
  const float* W3  = (const float*)d_in[14];
  const float* b3  = (const float*)d_in[15];
  const float* g3  = (const float*)d_in[16];
  const float* be3 = (const float*)d_in[17];
  const float* W4  = (const float*)d_in[18];
  const float* b4  = (const float*)d_in[19];

  const int n = in_sizes[0] / 128;   // 50000
  const int E = in_sizes[1] / 2;     // 800000
  const int L = in_sizes[3] / 2;     // 1000
  const int* src = ei;
  const int* dst = ei + E;
  const int* li0 = li;
  const int* li1 = li + L;
  const int NBK = (n + 255) / 256;   // dst buckets (<=256 for n<=65536)

  char* base = (char*)d_ws;
  size_t off = 0;
  auto alloc = [&](size_t bytes) -> void* {
    void* p = (void*)(base + off);
    off = (off + bytes + 255) & ~(size_t)255;
    return p;
  };
  int*   H      = (int*)alloc((size_t)NBK * NCH * 4);
  int*   O      = (int*)alloc((size_t)NBK * NCH * 4);
  int*   hsum   = (int*)alloc(1024 * 4);
  int*   ebuf   = (int*)alloc((size_t)E * 4);
  int*   eidx   = (int*)alloc((size_t)E * 4);
  int*   rowptr = (int*)alloc((size_t)(n + 1) * 4);
  float* dinv   = (float*)alloc((size_t)n * 4);
  float* invcnt = (float*)alloc((size_t)n * 4);
  float* stats1 = (float*)alloc(256 * 4);
  float* stats2 = (float*)alloc(128 * 4);
  float* stats3 = (float*)alloc(64 * 4);
  float* partials = (float*)alloc((size_t)256 * 256 * 4);
  float* gpool  = (float*)alloc((size_t)NGMAX * 32 * 4);
  unsigned short* h1b  = (unsigned short*)alloc((size_t)n * 128 * 2); // dinv*(x@W1)
  unsigned short* a1b  = (unsigned short*)alloc((size_t)n * 128 * 2); // pre-BN a1
  unsigned short* t1b  = (unsigned short*)alloc((size_t)n * 64 * 2);  // h1'@Wl2
  float*          t2f  = (float*)alloc((size_t)n * 64 * 4);           // h1'@Wr2+bl2
  unsigned short* h2b  = (unsigned short*)alloc((size_t)n * 64 * 2);  // pre-BN h2
  unsigned short* h3gb = (unsigned short*)alloc((size_t)n * 32 * 2);  // dinv*(h2'@W3)
  unsigned short* a3b  = (unsigned short*)alloc((size_t)n * 32 * 2);  // pre-BN a3
  unsigned short* h4b  = (unsigned short*)alloc((size_t)n * 32 * 2);  // dinv*(h3'@W4)
  float*          a4f  = (float*)alloc((size_t)n * 32 * 4);           // a4 (fp32)
  (void)ws_size; (void)n_in; (void)out_size;

  const int BT = 256;
  auto cdiv = [](long long a, long long b) { return (int)((a + b - 1) / b); };
  const int GB  = cdiv(n, 4);                 // gather grid
  const int GM  = cdiv(n, 64);                // mfma gemm grid
  const int MH  = NBK * NCH;                  // histogram elements
  const int NBH = cdiv(MH, 256);              // scan blocks

  // ---- CSR build: bucketed counting sort ----
  k_hist<<<NCH, 256, 0, stream>>>(dst, H, E, NBK);
  k_gscan1<<<NBH, 256, 0, stream>>>(H, hsum, MH);
  k_gscan2<<<1, 256, 0, stream>>>(hsum, NBH);
  k_gscan3<<<NBH, 256, 0, stream>>>(H, hsum, O, MH);
  k_scatter_bkt<<<NCH, 256, 0, stream>>>(src, dst, O, ebuf, E, NBK);
  k_fill2<<<NBK, 256, 0, stream>>>(ebuf, O, eidx, rowptr, dinv, invcnt, E, n, NBK);

  // ---- L1: GCN 128->128 (MFMA) ----
  k_gemm_mfma<128,128,false,false><<<GM, 256, 0, stream>>>(
      x, W1, nullptr, dinv, h1b, n);
  k_gather<128,true,true,false><<<GB, 256, 0, stream>>>(
      h1b, dinv, rowptr, eidx, b1, nullptr, nullptr, a1b, n);
  k_bn_stats<128><<<256, 256, 0, stream>>>(a1b, partials, n);
  k_bn_finalize<<<1, 128, 0, stream>>>(partials, stats1, g1, be1, 128, 1.0f / n);

  // ---- L2: SAGE 128->64 (MFMA dual, BN1+lrelu fused) ----
  k_gemm_sage_mfma<<<GM, 256, 0, stream>>>(a1b, Wl2, Wr2, bl2, stats1, t1b, t2f, n);
  k_gather<64,false,true,true><<<GB, 256, 0, stream>>>(
      t1b, invcnt, rowptr, eidx, nullptr, t2f, nullptr, h2b, n);
  k_bn_stats<64><<<256, 256, 0, stream>>>(h2b, partials, n);
  k_bn_finalize<<<1, 64, 0, stream>>>(partials, stats2, g2, be2, 64, 1.0f / n);

  // ---- L3: GCN 64->32 (MFMA, BN2+lrelu fused) ----
  k_gemm_mfma<64,32,true,true><<<GM, 256, 0, stream>>>(
      h2b, W3, stats2, dinv, h3gb, n);
  k_gather<32,true,true,false><<<GB, 256, 0, stream>>>(
      h3gb, dinv, rowptr, eidx, b3, nullptr, nullptr, a3b, n);
  k_bn_stats<32><<<256, 256, 0, stream>>>(a3b, partials, n);
  k_bn_finalize<<<1, 32, 0, stream>>>(partials, stats3, g3, be3, 32, 1.0f / n);

  // ---- L4: GCN 32->32 (MFMA, BN3+lrelu fused), fp32 out via gather ----
  k_gemm_mfma<32,32,true,true><<<GM, 256, 0, stream>>>(
      a3b, W4, stats3, dinv, h4b, n);
  k_gather<32,true,false,false><<<GB, 256, 0, stream>>>(
      h4b, dinv, rowptr, eidx, b4, nullptr, a4f, nullptr, n);

  // ---- pool (no atomics; batch sorted) + link ----
  k_pool2<<<NGMAX / 4, 256, 0, stream>>>(a4f, batch, gpool, n);
  k_link<<<cdiv(L, BT), BT, 0, stream>>>(gpool, li0, li1, (float*)d_out, L);
}